// Round 1
// baseline (1369.479 us; speedup 1.0000x reference)
//
#include <hip/hip_runtime.h>
#include <cstdint>
#include <cstddef>

typedef _Float16 HT;
typedef _Float16 h8 __attribute__((ext_vector_type(8)));
typedef float f32x4 __attribute__((ext_vector_type(4)));

constexpr int Tn  = 2048;   // sequence length
constexpr int Dm  = 2048;   // model dim
constexpr int Hh  = 16;     // heads
constexpr int NDc = 128;    // nope dim
constexpr int RDc = 64;     // rope dim
constexpr int VDc = 128;    // v dim
constexpr int QRc = 1536;   // q latent rank
constexpr int KVRc= 512;    // kv latent rank
constexpr int BT  = 4096;   // B*T

__device__ __forceinline__ f32x4 mfma16(h8 a, h8 b, f32x4 c) {
    return __builtin_amdgcn_mfma_f32_16x16x32_f16(a, b, c, 0, 0, 0);
}

// ---------------------------------------------------------------------------
// Generic C = A[MxK] @ B[KxN], B fp32 row-major, MFMA fp16, 128x128 tile.
// A: fp32 or fp16.  C: fp32 or fp16.
// ---------------------------------------------------------------------------
template<typename AT, typename CT>
__global__ __launch_bounds__(256)
void gemm_kernel(const AT* __restrict__ A, const float* __restrict__ Bw,
                 CT* __restrict__ C, int N, int K)
{
    __shared__ HT As[128][40];   // [m][k], stride 40 halves (80B) -> uniform b128 banking
    __shared__ HT Bs[128][40];   // [n][k] (transposed)

    const int tid  = threadIdx.x;
    const int lane = tid & 63;
    const int l15  = lane & 15, l4 = lane >> 4;
    const int wid  = tid >> 6;
    const int wr   = wid >> 1, wc = wid & 1;
    const int m0   = blockIdx.y * 128;
    const int n0   = blockIdx.x * 128;

    // staging assignment
    const int ar = tid >> 1, ak = (tid & 1) * 16;   // A: row, k-half
    const int bn = tid >> 1, bk = (tid & 1) * 16;   // B: col(n), k-half

    f32x4 acc[4][4] = {};

    for (int kt = 0; kt < K; kt += 32) {
        __syncthreads();
        { // stage A tile (convert to fp16 if needed)
            const AT* src = A + (size_t)(m0 + ar) * K + kt + ak;
            h8 h0, h1;
            if constexpr (sizeof(AT) == 4) {
                f32x4 v0 = *reinterpret_cast<const f32x4*>(src);
                f32x4 v1 = *reinterpret_cast<const f32x4*>(src + 4);
                f32x4 v2 = *reinterpret_cast<const f32x4*>(src + 8);
                f32x4 v3 = *reinterpret_cast<const f32x4*>(src + 12);
                #pragma unroll
                for (int i = 0; i < 4; i++) { h0[i] = (HT)v0[i]; h0[4+i] = (HT)v1[i]; }
                #pragma unroll
                for (int i = 0; i < 4; i++) { h1[i] = (HT)v2[i]; h1[4+i] = (HT)v3[i]; }
            } else {
                h0 = *reinterpret_cast<const h8*>(src);
                h1 = *reinterpret_cast<const h8*>(src + 8);
            }
            *reinterpret_cast<h8*>(&As[ar][ak])     = h0;
            *reinterpret_cast<h8*>(&As[ar][ak + 8]) = h1;
        }
        { // stage B tile transposed: Bs[n][k] = B[kt+k][n0+n]
            const float* src = Bw + (size_t)(kt + bk) * N + n0 + bn;
            h8 h0, h1;
            #pragma unroll
            for (int j = 0; j < 8; j++) h0[j] = (HT)src[(size_t)j * N];
            #pragma unroll
            for (int j = 0; j < 8; j++) h1[j] = (HT)src[(size_t)(8 + j) * N];
            *reinterpret_cast<h8*>(&Bs[bn][bk])     = h0;
            *reinterpret_cast<h8*>(&Bs[bn][bk + 8]) = h1;
        }
        __syncthreads();

        h8 af[4], bf[4];
        #pragma unroll
        for (int f = 0; f < 4; f++)
            af[f] = *reinterpret_cast<const h8*>(&As[wr*64 + f*16 + l15][l4*8]);
        #pragma unroll
        for (int g = 0; g < 4; g++)
            bf[g] = *reinterpret_cast<const h8*>(&Bs[wc*64 + g*16 + l15][l4*8]);
        #pragma unroll
        for (int f = 0; f < 4; f++)
            #pragma unroll
            for (int g = 0; g < 4; g++)
                acc[f][g] = mfma16(af[f], bf[g], acc[f][g]);
    }

    #pragma unroll
    for (int f = 0; f < 4; f++) {
        #pragma unroll
        for (int g = 0; g < 4; g++) {
            const int row = m0 + wr*64 + f*16 + l4*4;
            const int col = n0 + wc*64 + g*16 + l15;
            #pragma unroll
            for (int r = 0; r < 4; r++)
                C[(size_t)(row + r) * N + col] = (CT)acc[f][g][r];
        }
    }
}

// ---------------------------------------------------------------------------
// In-place RMSNorm over rows of fp16 matrix [BT][N], fp32 gain.
// ---------------------------------------------------------------------------
__global__ __launch_bounds__(256)
void rmsnorm_kernel(HT* __restrict__ X, const float* __restrict__ g, int N)
{
    const int row = blockIdx.x;
    HT* x = X + (size_t)row * N;
    float ss = 0.f;
    for (int i = threadIdx.x; i < N; i += 256) {
        float v = (float)x[i];
        ss += v * v;
    }
    #pragma unroll
    for (int sh = 32; sh >= 1; sh >>= 1) ss += __shfl_xor(ss, sh);
    __shared__ float red[4];
    if ((threadIdx.x & 63) == 0) red[threadIdx.x >> 6] = ss;
    __syncthreads();
    const float tot = red[0] + red[1] + red[2] + red[3];
    const float scale = rsqrtf(tot / (float)N + 1e-6f);
    for (int i = threadIdx.x; i < N; i += 256)
        x[i] = (HT)((float)x[i] * scale * g[i]);
}

// ---------------------------------------------------------------------------
// k_rope = rope(x @ w_k_rope)  -> fp32 [BT][64]. One 64-thread block per row.
// ---------------------------------------------------------------------------
__global__ __launch_bounds__(64)
void krope_kernel(const float* __restrict__ x, const float* __restrict__ w,
                  float* __restrict__ kr)
{
    const int bt = blockIdx.x;
    const int d  = threadIdx.x;           // 0..63
    const float* xr = x + (size_t)bt * Dm;
    float sum = 0.f;
    #pragma unroll 8
    for (int k = 0; k < Dm; k++) sum += xr[k] * w[(size_t)k * RDc + d];

    const int t = bt & (Tn - 1);
    const int i = d >> 1;
    const float ang = (float)t * exp2f(-(2.f * (float)i / 64.f) * 13.287712379549449f);
    const float c = cosf(ang), s = sinf(ang);
    const float partner = __shfl_xor(sum, 1);
    float o;
    if ((d & 1) == 0) o = sum * c - partner * s;      // o1 = x1*c - x2*s
    else              o = partner * s + sum * c;      // o2 = x1*s + x2*c
    kr[(size_t)bt * RDc + d] = o;
}

// ---------------------------------------------------------------------------
// In-place RoPE on q_rope fp16 [BT][H][64]; one thread per (even,odd) pair.
// ---------------------------------------------------------------------------
__global__ __launch_bounds__(256)
void ropeq_kernel(HT* __restrict__ qr)
{
    const int idx = blockIdx.x * 256 + threadIdx.x;
    if (idx >= BT * Hh * (RDc / 2)) return;
    const int i  = idx & 31;
    const int h  = (idx >> 5) & 15;
    const int bt = idx >> 9;
    const int t  = bt & (Tn - 1);
    const float ang = (float)t * exp2f(-(2.f * (float)i / 64.f) * 13.287712379549449f);
    const float c = cosf(ang), s = sinf(ang);
    HT* p = qr + (size_t)bt * (Hh * RDc) + h * RDc + 2 * i;
    const float x1 = (float)p[0], x2 = (float)p[1];
    p[0] = (HT)(x1 * c - x2 * s);
    p[1] = (HT)(x1 * s + x2 * c);
}

// ---------------------------------------------------------------------------
// Pack k output: fp32 (B,H,T,192) from k_nope fp16 [BT][H*128] + k_rope fp32 [BT][64]
// ---------------------------------------------------------------------------
__global__ __launch_bounds__(256)
void packk_kernel(const HT* __restrict__ kn, const float* __restrict__ kr,
                  float* __restrict__ ko)
{
    const size_t idx = (size_t)blockIdx.x * 256 + threadIdx.x;
    if (idx >= (size_t)2 * Hh * Tn * 192) return;
    const int d   = (int)(idx % 192);
    const size_t r = idx / 192;
    const int t = (int)(r & (Tn - 1));
    const int h = (int)((r >> 11) & 15);
    const int b = (int)(r >> 15);
    const size_t bt = (size_t)b * Tn + t;
    float v;
    if (d < 128) v = (float)kn[bt * (Hh * NDc) + h * NDc + d];
    else         v = kr[bt * RDc + (d - 128)];
    ko[idx] = v;
}

// ---------------------------------------------------------------------------
// Pack v_t output: fp32 (B,H,T,128) from v fp16 [BT][H*128]
// ---------------------------------------------------------------------------
__global__ __launch_bounds__(256)
void packv_kernel(const HT* __restrict__ vb, float* __restrict__ vo)
{
    const size_t idx = (size_t)blockIdx.x * 256 + threadIdx.x;
    if (idx >= (size_t)2 * Hh * Tn * 128) return;
    const int d   = (int)(idx & 127);
    const size_t r = idx >> 7;
    const int t = (int)(r & (Tn - 1));
    const int h = (int)((r >> 11) & 15);
    const int b = (int)(r >> 15);
    vo[idx] = (float)vb[((size_t)b * Tn + t) * (Hh * VDc) + h * VDc + d];
}

// ---------------------------------------------------------------------------
// Causal flash attention. Grid (T/64, H, B), 4 waves; wave = 16 q-rows.
// Writes attn_out fp16 [BT][H*128] (token-major, ready for output GEMM).
// ---------------------------------------------------------------------------
__global__ __launch_bounds__(256)
void attn_kernel(const HT* __restrict__ qn, const HT* __restrict__ qr,
                 const HT* __restrict__ kn, const float* __restrict__ krf,
                 const HT* __restrict__ vb, HT* __restrict__ ao)
{
    __shared__ HT Ps[4][16][40];   // per-wave P tile [q][k], stride 40

    const int tid  = threadIdx.x;
    const int lane = tid & 63;
    const int l15  = lane & 15, l4 = lane >> 4;
    const int w    = tid >> 6;
    const int q0   = blockIdx.x * 64;
    const int h    = blockIdx.y;
    const int b    = blockIdx.z;
    const int qw   = q0 + w * 16;

    // hoist Q fragments (192 dims = 6 frags of K=32)
    h8 aq[6];
    {
        const size_t rq = (size_t)b * Tn + qw + l15;
        const HT* pn = qn + rq * (Hh * NDc) + h * NDc + l4 * 8;
        #pragma unroll
        for (int f = 0; f < 4; f++) aq[f] = *reinterpret_cast<const h8*>(pn + f * 32);
        const HT* pr = qr + rq * (Hh * RDc) + h * RDc + l4 * 8;
        aq[4] = *reinterpret_cast<const h8*>(pr);
        aq[5] = *reinterpret_cast<const h8*>(pr + 32);
    }

    f32x4 o[8] = {};
    float m_i[4] = {-1e30f, -1e30f, -1e30f, -1e30f};
    float l_i[4] = {0.f, 0.f, 0.f, 0.f};

    const int kend = qw + 16;                    // per-wave causal limit
    for (int kb = 0; kb < kend; kb += 32) {
        // ---- S = Q K^T for 32 k-cols (two 16-col halves) ----
        f32x4 s0 = {}, s1 = {};
        {
            const size_t r0 = (size_t)b * Tn + kb + l15;
            const HT* p0 = kn + r0 * (Hh * NDc) + h * NDc + l4 * 8;
            const HT* p1 = p0 + (size_t)16 * (Hh * NDc);
            #pragma unroll
            for (int f = 0; f < 4; f++) {
                s0 = mfma16(aq[f], *reinterpret_cast<const h8*>(p0 + f * 32), s0);
                s1 = mfma16(aq[f], *reinterpret_cast<const h8*>(p1 + f * 32), s1);
            }
            const float* c0p = krf + r0 * RDc + l4 * 8;
            const float* c1p = c0p + (size_t)16 * RDc;
            #pragma unroll
            for (int f = 0; f < 2; f++) {
                h8 b0, b1;
                #pragma unroll
                for (int j = 0; j < 8; j++) {
                    b0[j] = (HT)c0p[f * 32 + j];
                    b1[j] = (HT)c1p[f * 32 + j];
                }
                s0 = mfma16(aq[4 + f], b0, s0);
                s1 = mfma16(aq[4 + f], b1, s1);
            }
        }
        // ---- online softmax (rows live across 16-lane groups) ----
        const float scl = 0.07216878364870323f;  // 1/sqrt(192)
        float e0v[4], e1v[4], alpha[4];
        #pragma unroll
        for (int r = 0; r < 4; r++) {
            const int qrow = qw + l4 * 4 + r;
            float a0 = (kb + l15      <= qrow) ? s0[r] * scl : -1e30f;
            float a1 = (kb + 16 + l15 <= qrow) ? s1[r] * scl : -1e30f;
            float mx = fmaxf(a0, a1);
            #pragma unroll
            for (int sh = 1; sh < 16; sh <<= 1) mx = fmaxf(mx, __shfl_xor(mx, sh));
            const float mn = fmaxf(m_i[r], mx);
            const float al = __expf(m_i[r] - mn);
            m_i[r] = mn;
            const float e0 = __expf(a0 - mn);
            const float e1 = __expf(a1 - mn);
            float rs = e0 + e1;
            #pragma unroll
            for (int sh = 1; sh < 16; sh <<= 1) rs += __shfl_xor(rs, sh);
            l_i[r] = l_i[r] * al + rs;
            alpha[r] = al; e0v[r] = e0; e1v[r] = e1;
        }
        #pragma unroll
        for (int g = 0; g < 8; g++)
            #pragma unroll
            for (int r = 0; r < 4; r++) o[g][r] *= alpha[r];

        // ---- P through LDS -> A-fragment layout ----
        #pragma unroll
        for (int r = 0; r < 4; r++) {
            Ps[w][l4 * 4 + r][l15]      = (HT)e0v[r];
            Ps[w][l4 * 4 + r][16 + l15] = (HT)e1v[r];
        }
        const h8 ap = *reinterpret_cast<const h8*>(&Ps[w][l15][l4 * 8]);

        // ---- O += P @ V ----
        {
            const HT* vp = vb + ((size_t)b * Tn + kb + l4 * 8) * (Hh * VDc) + h * VDc + l15;
            #pragma unroll
            for (int g = 0; g < 8; g++) {
                h8 vf;
                #pragma unroll
                for (int j = 0; j < 8; j++) vf[j] = vp[(size_t)j * (Hh * VDc) + g * 16];
                o[g] = mfma16(ap, vf, o[g]);
            }
        }
    }

    // ---- normalize + store ----
    const size_t orow = (size_t)b * Tn + qw + l4 * 4;
    #pragma unroll
    for (int r = 0; r < 4; r++) {
        const float inv = 1.0f / l_i[r];
        HT* dst = ao + (orow + r) * (Hh * VDc) + h * VDc + l15;
        #pragma unroll
        for (int g = 0; g < 8; g++) dst[g * 16] = (HT)(o[g][r] * inv);
    }
}

// ---------------------------------------------------------------------------
extern "C" void kernel_launch(void* const* d_in, const int* in_sizes, int n_in,
                              void* d_out, int out_size, void* d_ws, size_t ws_size,
                              hipStream_t stream)
{
    const float* x     = (const float*)d_in[0];
    const float* w_cq  = (const float*)d_in[1];
    const float* g_q   = (const float*)d_in[2];
    const float* w_ckv = (const float*)d_in[3];
    const float* g_kv  = (const float*)d_in[4];
    const float* w_dqn = (const float*)d_in[5];
    const float* w_dqr = (const float*)d_in[6];
    const float* w_dkn = (const float*)d_in[7];
    const float* w_dv  = (const float*)d_in[8];
    const float* w_kr  = (const float*)d_in[9];
    const float* w_out = (const float*)d_in[10];

    char* ws = (char*)d_ws;
    HT*    cq   = (HT*)(ws + 0);          // [BT][1536] q latent (dead after up-proj)
    HT*    ckv  = (HT*)(ws + 12582912);   // [BT][512]  kv latent
    HT*    qn   = (HT*)(ws + 16777216);   // [BT][2048] q_nope
    HT*    qr   = (HT*)(ws + 33554432);   // [BT][1024] q_rope
    HT*    kn   = (HT*)(ws + 41943040);   // [BT][2048] k_nope
    HT*    vbuf = (HT*)(ws + 58720256);   // [BT][2048] v
    float* krf  = (float*)(ws + 75497472);// [BT][64]   k_rope fp32
    HT*    ao   = (HT*)(ws + 0);          // [BT][2048] attn out (aliases cq+ckv, both dead)

    float* out_o = (float*)d_out;                          // (B,T,D)
    float* out_k = out_o + (size_t)BT * Dm;                // (B,H,T,192)
    float* out_v = out_k + (size_t)2 * Hh * Tn * 192;      // (B,H,T,128)

    const dim3 blk(256);
    // latent projections
    gemm_kernel<float, HT><<<dim3(QRc/128,  BT/128), blk, 0, stream>>>(x, w_cq,  cq,  QRc,  Dm);
    gemm_kernel<float, HT><<<dim3(KVRc/128, BT/128), blk, 0, stream>>>(x, w_ckv, ckv, KVRc, Dm);
    rmsnorm_kernel<<<dim3(BT), blk, 0, stream>>>(cq,  g_q,  QRc);
    rmsnorm_kernel<<<dim3(BT), blk, 0, stream>>>(ckv, g_kv, KVRc);
    // up-projections
    gemm_kernel<HT, HT><<<dim3((Hh*NDc)/128, BT/128), blk, 0, stream>>>(cq,  w_dqn, qn,   Hh*NDc, QRc);
    gemm_kernel<HT, HT><<<dim3((Hh*RDc)/128, BT/128), blk, 0, stream>>>(cq,  w_dqr, qr,   Hh*RDc, QRc);
    gemm_kernel<HT, HT><<<dim3((Hh*NDc)/128, BT/128), blk, 0, stream>>>(ckv, w_dkn, kn,   Hh*NDc, KVRc);
    gemm_kernel<HT, HT><<<dim3((Hh*VDc)/128, BT/128), blk, 0, stream>>>(ckv, w_dv,  vbuf, Hh*VDc, KVRc);
    // rope paths
    krope_kernel<<<dim3(BT), dim3(64), 0, stream>>>(x, w_kr, krf);
    ropeq_kernel<<<dim3((BT*Hh*(RDc/2))/256), blk, 0, stream>>>(qr);
    // k / v_t outputs
    packk_kernel<<<dim3((unsigned)(((size_t)2*Hh*Tn*192)/256)), blk, 0, stream>>>(kn, krf, out_k);
    packv_kernel<<<dim3((unsigned)(((size_t)2*Hh*Tn*128)/256)), blk, 0, stream>>>(vbuf, out_v);
    // attention
    attn_kernel<<<dim3(Tn/64, Hh, 2), blk, 0, stream>>>(qn, qr, kn, krf, vbuf, ao);
    // output projection
    gemm_kernel<HT, float><<<dim3(Dm/128, BT/128), blk, 0, stream>>>(ao, w_out, out_o, Dm, Hh*VDc);
}

// Round 2
// 1062.338 us; speedup vs baseline: 1.2891x; 1.2891x over previous
//
#include <hip/hip_runtime.h>
#include <cstdint>
#include <cstddef>

typedef _Float16 HT;
typedef _Float16 h8 __attribute__((ext_vector_type(8)));
typedef float f32x4 __attribute__((ext_vector_type(4)));

constexpr int Tn  = 2048;   // sequence length
constexpr int Dm  = 2048;   // model dim
constexpr int Hh  = 16;     // heads
constexpr int NDc = 128;    // nope dim
constexpr int RDc = 64;     // rope dim
constexpr int VDc = 128;    // v dim
constexpr int QRc = 1536;   // q latent rank
constexpr int KVRc= 512;    // kv latent rank
constexpr int BT  = 4096;   // B*T

__device__ __forceinline__ f32x4 mfma16(h8 a, h8 b, f32x4 c) {
    return __builtin_amdgcn_mfma_f32_16x16x32_f16(a, b, c, 0, 0, 0);
}

// ---------------------------------------------------------------------------
// Generic C = A[MxK] @ B[KxN], B fp32 row-major, MFMA fp16, 128x128 tile.
// ---------------------------------------------------------------------------
template<typename AT, typename CT>
__global__ __launch_bounds__(256)
void gemm_kernel(const AT* __restrict__ A, const float* __restrict__ Bw,
                 CT* __restrict__ C, int N, int K)
{
    __shared__ HT As[128][40];
    __shared__ HT Bs[128][40];

    const int tid  = threadIdx.x;
    const int lane = tid & 63;
    const int l15  = lane & 15, l4 = lane >> 4;
    const int wid  = tid >> 6;
    const int wr   = wid >> 1, wc = wid & 1;
    const int m0   = blockIdx.y * 128;
    const int n0   = blockIdx.x * 128;

    const int ar = tid >> 1, ak = (tid & 1) * 16;
    const int bn = tid >> 1, bk = (tid & 1) * 16;

    f32x4 acc[4][4] = {};

    for (int kt = 0; kt < K; kt += 32) {
        __syncthreads();
        {
            const AT* src = A + (size_t)(m0 + ar) * K + kt + ak;
            h8 h0, h1;
            if constexpr (sizeof(AT) == 4) {
                f32x4 v0 = *reinterpret_cast<const f32x4*>(src);
                f32x4 v1 = *reinterpret_cast<const f32x4*>(src + 4);
                f32x4 v2 = *reinterpret_cast<const f32x4*>(src + 8);
                f32x4 v3 = *reinterpret_cast<const f32x4*>(src + 12);
                #pragma unroll
                for (int i = 0; i < 4; i++) { h0[i] = (HT)v0[i]; h0[4+i] = (HT)v1[i]; }
                #pragma unroll
                for (int i = 0; i < 4; i++) { h1[i] = (HT)v2[i]; h1[4+i] = (HT)v3[i]; }
            } else {
                h0 = *reinterpret_cast<const h8*>(src);
                h1 = *reinterpret_cast<const h8*>(src + 8);
            }
            *reinterpret_cast<h8*>(&As[ar][ak])     = h0;
            *reinterpret_cast<h8*>(&As[ar][ak + 8]) = h1;
        }
        {
            const float* src = Bw + (size_t)(kt + bk) * N + n0 + bn;
            h8 h0, h1;
            #pragma unroll
            for (int j = 0; j < 8; j++) h0[j] = (HT)src[(size_t)j * N];
            #pragma unroll
            for (int j = 0; j < 8; j++) h1[j] = (HT)src[(size_t)(8 + j) * N];
            *reinterpret_cast<h8*>(&Bs[bn][bk])     = h0;
            *reinterpret_cast<h8*>(&Bs[bn][bk + 8]) = h1;
        }
        __syncthreads();

        h8 af[4], bf[4];
        #pragma unroll
        for (int f = 0; f < 4; f++)
            af[f] = *reinterpret_cast<const h8*>(&As[wr*64 + f*16 + l15][l4*8]);
        #pragma unroll
        for (int g = 0; g < 4; g++)
            bf[g] = *reinterpret_cast<const h8*>(&Bs[wc*64 + g*16 + l15][l4*8]);
        #pragma unroll
        for (int f = 0; f < 4; f++)
            #pragma unroll
            for (int g = 0; g < 4; g++)
                acc[f][g] = mfma16(af[f], bf[g], acc[f][g]);
    }

    #pragma unroll
    for (int f = 0; f < 4; f++) {
        #pragma unroll
        for (int g = 0; g < 4; g++) {
            const int row = m0 + wr*64 + f*16 + l4*4;
            const int col = n0 + wc*64 + g*16 + l15;
            #pragma unroll
            for (int r = 0; r < 4; r++)
                C[(size_t)(row + r) * N + col] = (CT)acc[f][g][r];
        }
    }
}

// ---------------------------------------------------------------------------
__global__ __launch_bounds__(256)
void rmsnorm_kernel(HT* __restrict__ X, const float* __restrict__ g, int N)
{
    const int row = blockIdx.x;
    HT* x = X + (size_t)row * N;
    float ss = 0.f;
    for (int i = threadIdx.x; i < N; i += 256) {
        float v = (float)x[i];
        ss += v * v;
    }
    #pragma unroll
    for (int sh = 32; sh >= 1; sh >>= 1) ss += __shfl_xor(ss, sh);
    __shared__ float red[4];
    if ((threadIdx.x & 63) == 0) red[threadIdx.x >> 6] = ss;
    __syncthreads();
    const float tot = red[0] + red[1] + red[2] + red[3];
    const float scale = rsqrtf(tot / (float)N + 1e-6f);
    for (int i = threadIdx.x; i < N; i += 256)
        x[i] = (HT)((float)x[i] * scale * g[i]);
}

// ---------------------------------------------------------------------------
// k_rope = rope(x @ w_k_rope) -> fp32 [BT][64] (for packk) + fp16 (for attn)
// ---------------------------------------------------------------------------
__global__ __launch_bounds__(64)
void krope_kernel(const float* __restrict__ x, const float* __restrict__ w,
                  float* __restrict__ kr, HT* __restrict__ kr16)
{
    const int bt = blockIdx.x;
    const int d  = threadIdx.x;
    const float* xr = x + (size_t)bt * Dm;
    float sum = 0.f;
    #pragma unroll 8
    for (int k = 0; k < Dm; k++) sum += xr[k] * w[(size_t)k * RDc + d];

    const int t = bt & (Tn - 1);
    const int i = d >> 1;
    const float ang = (float)t * exp2f(-(2.f * (float)i / 64.f) * 13.287712379549449f);
    const float c = cosf(ang), s = sinf(ang);
    const float partner = __shfl_xor(sum, 1);
    float o;
    if ((d & 1) == 0) o = sum * c - partner * s;
    else              o = partner * s + sum * c;
    kr[(size_t)bt * RDc + d]   = o;
    kr16[(size_t)bt * RDc + d] = (HT)o;
}

// ---------------------------------------------------------------------------
__global__ __launch_bounds__(256)
void ropeq_kernel(HT* __restrict__ qr)
{
    const int idx = blockIdx.x * 256 + threadIdx.x;
    if (idx >= BT * Hh * (RDc / 2)) return;
    const int i  = idx & 31;
    const int h  = (idx >> 5) & 15;
    const int bt = idx >> 9;
    const int t  = bt & (Tn - 1);
    const float ang = (float)t * exp2f(-(2.f * (float)i / 64.f) * 13.287712379549449f);
    const float c = cosf(ang), s = sinf(ang);
    HT* p = qr + (size_t)bt * (Hh * RDc) + h * RDc + 2 * i;
    const float x1 = (float)p[0], x2 = (float)p[1];
    p[0] = (HT)(x1 * c - x2 * s);
    p[1] = (HT)(x1 * s + x2 * c);
}

// ---------------------------------------------------------------------------
__global__ __launch_bounds__(256)
void packk_kernel(const HT* __restrict__ kn, const float* __restrict__ kr,
                  float* __restrict__ ko)
{
    const size_t idx = (size_t)blockIdx.x * 256 + threadIdx.x;
    if (idx >= (size_t)2 * Hh * Tn * 192) return;
    const int d   = (int)(idx % 192);
    const size_t r = idx / 192;
    const int t = (int)(r & (Tn - 1));
    const int h = (int)((r >> 11) & 15);
    const int b = (int)(r >> 15);
    const size_t bt = (size_t)b * Tn + t;
    float v;
    if (d < 128) v = (float)kn[bt * (Hh * NDc) + h * NDc + d];
    else         v = kr[bt * RDc + (d - 128)];
    ko[idx] = v;
}

// ---------------------------------------------------------------------------
// Pack v_t fp32 output AND build fp16 V^T [b][h][d][t] for attention.
// Grid (T/64, H, B), 256 threads, LDS transpose tile.
// ---------------------------------------------------------------------------
__global__ __launch_bounds__(256)
void packvt_kernel(const HT* __restrict__ vb, float* __restrict__ vo,
                   HT* __restrict__ vt)
{
    __shared__ HT Vs[64][136];
    const int tb = blockIdx.x, h = blockIdx.y, b = blockIdx.z;
    const int tid = threadIdx.x;

    const int t = tid >> 2, q = tid & 3;
    const HT* src = vb + ((size_t)b * Tn + (size_t)tb * 64 + t) * (Hh * VDc) + h * VDc + q * 32;
    float* vod = vo + (((size_t)(b * Hh + h)) * Tn + (size_t)tb * 64 + t) * VDc + q * 32;
    #pragma unroll
    for (int j = 0; j < 4; j++) {
        h8 v = *reinterpret_cast<const h8*>(src + j * 8);
        *reinterpret_cast<h8*>(&Vs[t][q * 32 + j * 8]) = v;
        f32x4 f0, f1;
        #pragma unroll
        for (int i = 0; i < 4; i++) { f0[i] = (float)v[i]; f1[i] = (float)v[4 + i]; }
        *reinterpret_cast<f32x4*>(vod + j * 8)     = f0;
        *reinterpret_cast<f32x4*>(vod + j * 8 + 4) = f1;
    }
    __syncthreads();
    const int d = tid >> 1, hf = tid & 1;
    HT* dst = vt + (((size_t)(b * Hh + h) * VDc) + d) * Tn + (size_t)tb * 64 + hf * 32;
    #pragma unroll
    for (int j = 0; j < 4; j++) {
        h8 v;
        #pragma unroll
        for (int i = 0; i < 8; i++) v[i] = Vs[hf * 32 + j * 8 + i][d];
        *reinterpret_cast<h8*>(dst + j * 8) = v;
    }
}

// ---------------------------------------------------------------------------
// Causal flash attention v2. Grid (16, H, B), 4 waves; each wave processes
// two mirrored 16-row q-tiles (tl and 127-tl) for uniform work. KBLK=64.
// K from kn (fp16, h-sliced rows) + kr16 (fp16, shared); V from vt (fp16 V^T).
// ---------------------------------------------------------------------------
__global__ __launch_bounds__(256)
void attn2_kernel(const HT* __restrict__ qn, const HT* __restrict__ qr,
                  const HT* __restrict__ kn, const HT* __restrict__ kr16,
                  const HT* __restrict__ vt, HT* __restrict__ ao)
{
    __shared__ HT Ps[4][16][72];
    const int tid  = threadIdx.x;
    const int lane = tid & 63;
    const int l15  = lane & 15, l4 = lane >> 4;
    const int w    = tid >> 6;
    const int h    = blockIdx.y;
    const int b    = blockIdx.z;
    const int tl   = blockIdx.x * 4 + w;

    const HT* vt_h = vt + ((size_t)(b * Hh + h) * VDc) * Tn;

    for (int ph = 0; ph < 2; ph++) {
        const int tile = ph ? (127 - tl) : tl;
        const int qw   = tile * 16;

        h8 aq[6];
        {
            const size_t rq = (size_t)b * Tn + qw + l15;
            const HT* pn = qn + rq * (Hh * NDc) + h * NDc + l4 * 8;
            #pragma unroll
            for (int f = 0; f < 4; f++) aq[f] = *reinterpret_cast<const h8*>(pn + f * 32);
            const HT* pr = qr + rq * (Hh * RDc) + h * RDc + l4 * 8;
            aq[4] = *reinterpret_cast<const h8*>(pr);
            aq[5] = *reinterpret_cast<const h8*>(pr + 32);
        }

        f32x4 o[8] = {};
        float m_i[4] = {-1e30f, -1e30f, -1e30f, -1e30f};
        float l_i[4] = {0.f, 0.f, 0.f, 0.f};

        const int kend = qw + 16;
        for (int kb = 0; kb < kend; kb += 64) {
            f32x4 s[4] = {};
            #pragma unroll
            for (int c = 0; c < 4; c++) {
                const size_t row = (size_t)b * Tn + kb + c * 16 + l15;
                const HT* kp = kn + row * (Hh * NDc) + h * NDc + l4 * 8;
                #pragma unroll
                for (int f = 0; f < 4; f++)
                    s[c] = mfma16(aq[f], *reinterpret_cast<const h8*>(kp + f * 32), s[c]);
                const HT* rp = kr16 + row * RDc + l4 * 8;
                s[c] = mfma16(aq[4], *reinterpret_cast<const h8*>(rp), s[c]);
                s[c] = mfma16(aq[5], *reinterpret_cast<const h8*>(rp + 32), s[c]);
            }

            const float scl = 0.07216878364870323f;   // 1/sqrt(192)
            float al[4];
            #pragma unroll
            for (int r = 0; r < 4; r++) {
                const int qrow = qw + l4 * 4 + r;
                float a[4];
                #pragma unroll
                for (int c = 0; c < 4; c++)
                    a[c] = (kb + c * 16 + l15 <= qrow) ? s[c][r] * scl : -1e30f;
                float mx = fmaxf(fmaxf(a[0], a[1]), fmaxf(a[2], a[3]));
                #pragma unroll
                for (int sh = 1; sh < 16; sh <<= 1) mx = fmaxf(mx, __shfl_xor(mx, sh));
                const float mn    = fmaxf(m_i[r], mx);
                const float alpha = __expf(m_i[r] - mn);
                m_i[r] = mn;
                float rs = 0.f;
                #pragma unroll
                for (int c = 0; c < 4; c++) {
                    const float e = __expf(a[c] - mn);
                    rs += e;
                    Ps[w][l4 * 4 + r][c * 16 + l15] = (HT)e;
                }
                #pragma unroll
                for (int sh = 1; sh < 16; sh <<= 1) rs += __shfl_xor(rs, sh);
                l_i[r] = l_i[r] * alpha + rs;
                al[r] = alpha;
            }
            #pragma unroll
            for (int g = 0; g < 8; g++)
                #pragma unroll
                for (int r = 0; r < 4; r++) o[g][r] *= al[r];

            const h8 ap0 = *reinterpret_cast<const h8*>(&Ps[w][l15][l4 * 8]);
            const h8 ap1 = *reinterpret_cast<const h8*>(&Ps[w][l15][32 + l4 * 8]);

            #pragma unroll
            for (int g = 0; g < 8; g++) {
                const HT* vg = vt_h + (size_t)(g * 16 + l15) * Tn + kb + l4 * 8;
                o[g] = mfma16(ap0, *reinterpret_cast<const h8*>(vg), o[g]);
                o[g] = mfma16(ap1, *reinterpret_cast<const h8*>(vg + 32), o[g]);
            }
        }

        const size_t orow = (size_t)b * Tn + qw + l4 * 4;
        #pragma unroll
        for (int r = 0; r < 4; r++) {
            const float inv = 1.0f / l_i[r];
            HT* dst = ao + (orow + r) * (Hh * VDc) + h * VDc + l15;
            #pragma unroll
            for (int g = 0; g < 8; g++) dst[g * 16] = (HT)(o[g][r] * inv);
        }
    }
}

// ---------------------------------------------------------------------------
extern "C" void kernel_launch(void* const* d_in, const int* in_sizes, int n_in,
                              void* d_out, int out_size, void* d_ws, size_t ws_size,
                              hipStream_t stream)
{
    const float* x     = (const float*)d_in[0];
    const float* w_cq  = (const float*)d_in[1];
    const float* g_q   = (const float*)d_in[2];
    const float* w_ckv = (const float*)d_in[3];
    const float* g_kv  = (const float*)d_in[4];
    const float* w_dqn = (const float*)d_in[5];
    const float* w_dqr = (const float*)d_in[6];
    const float* w_dkn = (const float*)d_in[7];
    const float* w_dv  = (const float*)d_in[8];
    const float* w_kr  = (const float*)d_in[9];
    const float* w_out = (const float*)d_in[10];

    char* ws = (char*)d_ws;
    HT*    cq   = (HT*)(ws + 0);            // [BT][1536]
    HT*    ckv  = (HT*)(ws + 12582912);     // [BT][512]
    HT*    qn   = (HT*)(ws + 16777216);     // [BT][2048]   (-> ao later)
    HT*    qr   = (HT*)(ws + 33554432);     // [BT][1024]
    HT*    kn   = (HT*)(ws + 41943040);     // [BT][2048]
    HT*    vbuf = (HT*)(ws + 58720256);     // [BT][2048]
    float* krf  = (float*)(ws + 75497472);  // [BT][64] fp32
    HT*    kr16 = (HT*)(ws + 76546048);     // [BT][64] fp16
    HT*    vt   = (HT*)(ws + 0);            // [2][16][128][2048] (aliases cq+ckv)
    HT*    ao   = qn;                       // aliases qn (safe: exact partition)

    float* out_o = (float*)d_out;                          // (B,T,D)
    float* out_k = out_o + (size_t)BT * Dm;                // (B,H,T,192)
    float* out_v = out_k + (size_t)2 * Hh * Tn * 192;      // (B,H,T,128)

    const dim3 blk(256);
    // latent projections
    gemm_kernel<float, HT><<<dim3(QRc/128,  BT/128), blk, 0, stream>>>(x, w_cq,  cq,  QRc,  Dm);
    gemm_kernel<float, HT><<<dim3(KVRc/128, BT/128), blk, 0, stream>>>(x, w_ckv, ckv, KVRc, Dm);
    rmsnorm_kernel<<<dim3(BT), blk, 0, stream>>>(cq,  g_q,  QRc);
    rmsnorm_kernel<<<dim3(BT), blk, 0, stream>>>(ckv, g_kv, KVRc);
    // up-projections
    gemm_kernel<HT, HT><<<dim3((Hh*NDc)/128, BT/128), blk, 0, stream>>>(cq,  w_dqn, qn,   Hh*NDc, QRc);
    gemm_kernel<HT, HT><<<dim3((Hh*RDc)/128, BT/128), blk, 0, stream>>>(cq,  w_dqr, qr,   Hh*RDc, QRc);
    gemm_kernel<HT, HT><<<dim3((Hh*NDc)/128, BT/128), blk, 0, stream>>>(ckv, w_dkn, kn,   Hh*NDc, KVRc);
    gemm_kernel<HT, HT><<<dim3((Hh*VDc)/128, BT/128), blk, 0, stream>>>(ckv, w_dv,  vbuf, Hh*VDc, KVRc);
    // rope paths
    krope_kernel<<<dim3(BT), dim3(64), 0, stream>>>(x, w_kr, krf, kr16);
    ropeq_kernel<<<dim3((BT*Hh*(RDc/2))/256), blk, 0, stream>>>(qr);
    // k / v_t outputs (+ fp16 V^T for attention)
    packk_kernel<<<dim3((unsigned)(((size_t)2*Hh*Tn*192)/256)), blk, 0, stream>>>(kn, krf, out_k);
    packvt_kernel<<<dim3(Tn/64, Hh, 2), blk, 0, stream>>>(vbuf, out_v, vt);
    // attention (balanced mirrored q-tiles)
    attn2_kernel<<<dim3(16, Hh, 2), blk, 0, stream>>>(qn, qr, kn, kr16, vt, ao);
    // output projection
    gemm_kernel<HT, float><<<dim3(Dm/128, BT/128), blk, 0, stream>>>(ao, w_out, out_o, Dm, Hh*VDc);
}

// Round 3
// 510.152 us; speedup vs baseline: 2.6845x; 2.0824x over previous
//
#include <hip/hip_runtime.h>
#include <cstdint>
#include <cstddef>

typedef _Float16 HT;
typedef _Float16 h8 __attribute__((ext_vector_type(8)));
typedef _Float16 h4 __attribute__((ext_vector_type(4)));
typedef float f32x4 __attribute__((ext_vector_type(4)));

constexpr int Tn  = 2048;
constexpr int Dm  = 2048;
constexpr int Hh  = 16;
constexpr int NDc = 128;
constexpr int RDc = 64;
constexpr int VDc = 128;
constexpr int QRc = 1536;
constexpr int KVRc= 512;
constexpr int BT  = 4096;

__device__ __forceinline__ f32x4 mfma16(h8 a, h8 b, f32x4 c) {
    return __builtin_amdgcn_mfma_f32_16x16x32_f16(a, b, c, 0, 0, 0);
}

// async global->LDS, 16B per lane; LDS dest = wave-uniform base + lane*16
__device__ __forceinline__ void gload_lds16(const void* g, void* l) {
    __builtin_amdgcn_global_load_lds(
        (const __attribute__((address_space(1))) unsigned int*)g,
        (__attribute__((address_space(3))) unsigned int*)l, 16, 0, 0);
}

// ---------------------------------------------------------------------------
// cos/sin table: cstab[t*32+i] = (cos, sin) of t * 10000^(-i/32)
// ---------------------------------------------------------------------------
__global__ __launch_bounds__(256)
void cstab_kernel(float2* __restrict__ cs)
{
    const int idx = blockIdx.x * 256 + threadIdx.x;   // 65536
    const int t = idx >> 5, i = idx & 31;
    const float ang = (float)t * exp2f(-(float)i * (13.287712379549449f / 32.f));
    cs[idx] = make_float2(cosf(ang), sinf(ang));
}

// ---------------------------------------------------------------------------
// Weight transpose+convert: src fp32 [K][N] -> dst fp16 [N][K]
// ---------------------------------------------------------------------------
__global__ __launch_bounds__(256)
void wtrans_kernel(const float* __restrict__ src, HT* __restrict__ dst,
                   int K, int N)
{
    __shared__ float Ts[64][65];
    const int k0 = blockIdx.y * 64, n0 = blockIdx.x * 64;
    const int tid = threadIdx.x;
    {
        const int r = tid >> 2, c0 = (tid & 3) * 16;
        const float* s = src + (size_t)(k0 + r) * N + n0 + c0;
        #pragma unroll
        for (int j = 0; j < 4; j++)
            *reinterpret_cast<f32x4*>(&Ts[r][c0 + j * 4]) = *reinterpret_cast<const f32x4*>(s + j * 4);
    }
    __syncthreads();
    {
        const int c = tid >> 2, kq = (tid & 3) * 16;
        h8 o0, o1;
        #pragma unroll
        for (int j = 0; j < 8; j++) { o0[j] = (HT)Ts[kq + j][c]; o1[j] = (HT)Ts[kq + 8 + j][c]; }
        HT* d = dst + (size_t)(n0 + c) * K + k0 + kq;
        *reinterpret_cast<h8*>(d)     = o0;
        *reinterpret_cast<h8*>(d + 8) = o1;
    }
}

// ---------------------------------------------------------------------------
__global__ __launch_bounds__(256)
void convx_kernel(const float* __restrict__ x, HT* __restrict__ x16)
{
    const size_t i = ((size_t)blockIdx.x * 256 + threadIdx.x) * 8;
    f32x4 a = *reinterpret_cast<const f32x4*>(x + i);
    f32x4 b = *reinterpret_cast<const f32x4*>(x + i + 4);
    h8 v;
    #pragma unroll
    for (int j = 0; j < 4; j++) { v[j] = (HT)a[j]; v[4 + j] = (HT)b[j]; }
    *reinterpret_cast<h8*>(x16 + i) = v;
}

// ---------------------------------------------------------------------------
// m97-style GEMM: A [M][K] (fp16 glds, or fp32 reg-staged), Bt fp16 [N][K],
// 128x128 tile, BK=32, 4 waves, 4x4 frags. EPI: 0 plain, 1 rope->qr,
// 2 kn+out_k(nope), 3 vt+out_v.
// ---------------------------------------------------------------------------
template<bool AFP32, int EPI, typename CT>
__global__ __launch_bounds__(256)
void gemm16(const void* __restrict__ Av, const HT* __restrict__ Bt,
            CT* __restrict__ C, const int N, const int K,
            HT* __restrict__ aux1, float* __restrict__ aux2,
            const float2* __restrict__ cstab)
{
    __shared__ HT As[128 * 32];
    __shared__ HT Bs[128 * 32];

    const int tid  = threadIdx.x;
    const int lane = tid & 63;
    const int l15  = lane & 15, l4 = lane >> 4;
    const int w    = tid >> 6;
    const int wr   = w >> 1, wc = w & 1;
    const int m0   = blockIdx.y * 128;
    const int n0   = blockIdx.x * 128;

    f32x4 acc[4][4] = {};

    for (int kt = 0; kt < K; kt += 32) {
        __syncthreads();
        if constexpr (AFP32) {
            const float* src = (const float*)Av + (size_t)(m0 + (tid >> 1)) * K + kt + (tid & 1) * 16;
            f32x4 v0 = *reinterpret_cast<const f32x4*>(src);
            f32x4 v1 = *reinterpret_cast<const f32x4*>(src + 4);
            f32x4 v2 = *reinterpret_cast<const f32x4*>(src + 8);
            f32x4 v3 = *reinterpret_cast<const f32x4*>(src + 12);
            h8 h0, h1;
            #pragma unroll
            for (int i = 0; i < 4; i++) { h0[i] = (HT)v0[i]; h0[4+i] = (HT)v1[i];
                                          h1[i] = (HT)v2[i]; h1[4+i] = (HT)v3[i]; }
            HT* dstp = &As[(tid >> 1) * 32 + (tid & 1) * 16];
            *reinterpret_cast<h8*>(dstp)     = h0;
            *reinterpret_cast<h8*>(dstp + 8) = h1;
        } else {
            #pragma unroll
            for (int i = 0; i < 2; i++) {
                const int row = (w * 2 + i) * 16 + (lane >> 2);
                gload_lds16((const HT*)Av + (size_t)(m0 + row) * K + kt + (lane & 3) * 8,
                            &As[(w * 2 + i) * 512]);
            }
        }
        #pragma unroll
        for (int i = 0; i < 2; i++) {
            const int row = (w * 2 + i) * 16 + (lane >> 2);
            gload_lds16(Bt + (size_t)(n0 + row) * K + kt + (lane & 3) * 8,
                        &Bs[(w * 2 + i) * 512]);
        }
        __syncthreads();

        h8 af[4], bf[4];
        #pragma unroll
        for (int f = 0; f < 4; f++)
            af[f] = *reinterpret_cast<const h8*>(&As[(wr * 64 + f * 16 + l15) * 32 + l4 * 8]);
        #pragma unroll
        for (int g = 0; g < 4; g++)
            bf[g] = *reinterpret_cast<const h8*>(&Bs[(wc * 64 + g * 16 + l15) * 32 + l4 * 8]);
        #pragma unroll
        for (int f = 0; f < 4; f++)
            #pragma unroll
            for (int g = 0; g < 4; g++)
                acc[f][g] = mfma16(af[f], bf[g], acc[f][g]);
    }

    #pragma unroll
    for (int f = 0; f < 4; f++) {
        #pragma unroll
        for (int g = 0; g < 4; g++) {
            const int row = m0 + wr * 64 + f * 16 + l4 * 4;
            const int col = n0 + wc * 64 + g * 16 + l15;
            if constexpr (EPI == 0) {
                #pragma unroll
                for (int r = 0; r < 4; r++)
                    C[(size_t)(row + r) * N + col] = (CT)acc[f][g][r];
            } else if constexpr (EPI == 1) {
                const int i = (col & 63) >> 1;
                const bool odd = col & 1;
                #pragma unroll
                for (int r = 0; r < 4; r++) {
                    const int t = (row + r) & (Tn - 1);
                    const float2 cs = cstab[t * 32 + i];
                    const float v = acc[f][g][r];
                    const float p = __shfl_xor(v, 1);
                    const float o = odd ? p * cs.y + v * cs.x : v * cs.x - p * cs.y;
                    C[(size_t)(row + r) * N + col] = (CT)o;
                }
            } else if constexpr (EPI == 2) {
                const int h = col >> 7, d = col & 127;
                #pragma unroll
                for (int r = 0; r < 4; r++) {
                    const int rw = row + r;
                    const int b = rw >> 11, t = rw & (Tn - 1);
                    C[(size_t)rw * N + col] = (CT)acc[f][g][r];
                    aux2[((size_t)(b * Hh + h) * Tn + t) * 192 + d] = acc[f][g][r];
                }
            } else {  // EPI == 3
                const int h = col >> 7, d = col & 127;
                const int b = row >> 11, t0 = row & (Tn - 1);
                h4 pk;
                #pragma unroll
                for (int r = 0; r < 4; r++) {
                    aux2[((size_t)(b * Hh + h) * Tn + t0 + r) * 128 + d] = acc[f][g][r];
                    pk[r] = (HT)acc[f][g][r];
                }
                *reinterpret_cast<h4*>(&aux1[((size_t)(b * Hh + h) * 128 + d) * Tn + t0]) = pk;
            }
        }
    }
}

// ---------------------------------------------------------------------------
// krope GEMM: x fp32 [BT][2048] @ w_krT fp16 [64][2048] -> kr16 fp16 (roped)
// ---------------------------------------------------------------------------
__global__ __launch_bounds__(256)
void krgemm_kernel(const float* __restrict__ x, const HT* __restrict__ wkrT,
                   HT* __restrict__ kr16, const float2* __restrict__ cstab)
{
    __shared__ HT As[128 * 32];
    __shared__ HT Bs[64 * 32];
    const int tid = threadIdx.x, lane = tid & 63, w = tid >> 6;
    const int l15 = lane & 15, l4 = lane >> 4;
    const int m0 = blockIdx.x * 128;

    f32x4 acc[2][4] = {};
    for (int kt = 0; kt < Dm; kt += 32) {
        __syncthreads();
        {
            const float* src = x + (size_t)(m0 + (tid >> 1)) * Dm + kt + (tid & 1) * 16;
            f32x4 v0 = *reinterpret_cast<const f32x4*>(src);
            f32x4 v1 = *reinterpret_cast<const f32x4*>(src + 4);
            f32x4 v2 = *reinterpret_cast<const f32x4*>(src + 8);
            f32x4 v3 = *reinterpret_cast<const f32x4*>(src + 12);
            h8 h0, h1;
            #pragma unroll
            for (int i = 0; i < 4; i++) { h0[i] = (HT)v0[i]; h0[4+i] = (HT)v1[i];
                                          h1[i] = (HT)v2[i]; h1[4+i] = (HT)v3[i]; }
            HT* dstp = &As[(tid >> 1) * 32 + (tid & 1) * 16];
            *reinterpret_cast<h8*>(dstp)     = h0;
            *reinterpret_cast<h8*>(dstp + 8) = h1;
        }
        gload_lds16(wkrT + (size_t)(w * 16 + (lane >> 2)) * Dm + kt + (lane & 3) * 8,
                    &Bs[w * 512]);
        __syncthreads();

        h8 af[2], bf[4];
        #pragma unroll
        for (int f = 0; f < 2; f++)
            af[f] = *reinterpret_cast<const h8*>(&As[(w * 32 + f * 16 + l15) * 32 + l4 * 8]);
        #pragma unroll
        for (int g = 0; g < 4; g++)
            bf[g] = *reinterpret_cast<const h8*>(&Bs[(g * 16 + l15) * 32 + l4 * 8]);
        #pragma unroll
        for (int f = 0; f < 2; f++)
            #pragma unroll
            for (int g = 0; g < 4; g++)
                acc[f][g] = mfma16(af[f], bf[g], acc[f][g]);
    }

    #pragma unroll
    for (int f = 0; f < 2; f++) {
        #pragma unroll
        for (int g = 0; g < 4; g++) {
            const int col = g * 16 + l15;
            const int i = col >> 1;
            const bool odd = col & 1;
            const int row = m0 + w * 32 + f * 16 + l4 * 4;
            #pragma unroll
            for (int r = 0; r < 4; r++) {
                const int t = (row + r) & (Tn - 1);
                const float2 cs = cstab[t * 32 + i];
                const float v = acc[f][g][r];
                const float p = __shfl_xor(v, 1);
                const float o = odd ? p * cs.y + v * cs.x : v * cs.x - p * cs.y;
                kr16[(size_t)(row + r) * 64 + col] = (HT)o;
            }
        }
    }
}

// ---------------------------------------------------------------------------
// broadcast rope slice of out_k across 16 heads (fp32)
// ---------------------------------------------------------------------------
__global__ __launch_bounds__(256)
void kropebc_kernel(const HT* __restrict__ kr16, float* __restrict__ out_k)
{
    const int idx = blockIdx.x * 256 + threadIdx.x;    // 2*2048*16
    const int j4 = (idx & 15) * 4;
    const int t  = (idx >> 4) & (Tn - 1);
    const int b  = idx >> 15;
    h4 v = *reinterpret_cast<const h4*>(&kr16[((size_t)(b * Tn + t)) * 64 + j4]);
    f32x4 f;
    #pragma unroll
    for (int r = 0; r < 4; r++) f[r] = (float)v[r];
    #pragma unroll
    for (int h = 0; h < Hh; h++)
        *reinterpret_cast<f32x4*>(&out_k[((size_t)(b * Hh + h) * Tn + t) * 192 + 128 + j4]) = f;
}

// ---------------------------------------------------------------------------
__global__ __launch_bounds__(256)
void rmsnorm_kernel(HT* __restrict__ X, const float* __restrict__ g, int N)
{
    const int row = blockIdx.x;
    HT* x = X + (size_t)row * N;
    float ss = 0.f;
    for (int i = threadIdx.x * 8; i < N; i += 2048) {
        h8 v = *reinterpret_cast<const h8*>(&x[i]);
        #pragma unroll
        for (int j = 0; j < 8; j++) { float f = (float)v[j]; ss += f * f; }
    }
    #pragma unroll
    for (int sh = 32; sh >= 1; sh >>= 1) ss += __shfl_xor(ss, sh);
    __shared__ float red[4];
    if ((threadIdx.x & 63) == 0) red[threadIdx.x >> 6] = ss;
    __syncthreads();
    const float tot = red[0] + red[1] + red[2] + red[3];
    const float scale = rsqrtf(tot / (float)N + 1e-6f);
    for (int i = threadIdx.x * 8; i < N; i += 2048) {
        h8 v = *reinterpret_cast<const h8*>(&x[i]);
        f32x4 g0 = *reinterpret_cast<const f32x4*>(&g[i]);
        f32x4 g1 = *reinterpret_cast<const f32x4*>(&g[i + 4]);
        #pragma unroll
        for (int j = 0; j < 4; j++) { v[j]   = (HT)((float)v[j]   * scale * g0[j]);
                                      v[4+j] = (HT)((float)v[4+j] * scale * g1[j]); }
        *reinterpret_cast<h8*>(&x[i]) = v;
    }
}

// ---------------------------------------------------------------------------
// Flash attention v3: LDS-staged K/V, mirrored-pair supertiles.
// Grid 512 blocks flat; block -> (pair tl, h, b) via XCD-chunked remap.
// ---------------------------------------------------------------------------
__global__ __launch_bounds__(256)
void attn3_kernel(const HT* __restrict__ qn, const HT* __restrict__ qr,
                  const HT* __restrict__ kn, const HT* __restrict__ kr16,
                  const HT* __restrict__ vt, HT* __restrict__ ao)
{
    __shared__ HT Ks_n[64 * 128];   // [krow][128] nope, src-swizzled chunks
    __shared__ HT Ks_r[64 * 64];    // [krow][64] rope
    __shared__ HT Vs[128 * 64];     // [d][64 t]
    __shared__ HT Ps[4][16][72];

    const int tid  = threadIdx.x;
    const int lane = tid & 63;
    const int l15  = lane & 15, l4 = lane >> 4;
    const int w    = tid >> 6;

    const int bid = blockIdx.x;                    // 512
    const int wid = (bid & 7) * 64 + (bid >> 3);   // XCD-chunked remap
    const int tl  = wid & 15;
    const int h   = (wid >> 4) & 15;
    const int b   = wid >> 8;

    const size_t bT = (size_t)b * Tn;
    const HT* vt_h = vt + ((size_t)(b * Hh + h) * 128) * Tn;

    for (int ph = 0; ph < 2; ph++) {
        const int tile = ph ? (31 - tl) : tl;
        const int qs = tile * 64;
        const int qw = qs + 16 * w;

        h8 aq[6];
        {
            const size_t rq = bT + qw + l15;
            const HT* pn = qn + rq * 2048 + h * 128 + l4 * 8;
            #pragma unroll
            for (int f = 0; f < 4; f++) aq[f] = *reinterpret_cast<const h8*>(pn + f * 32);
            const HT* pr = qr + rq * 1024 + h * 64 + l4 * 8;
            aq[4] = *reinterpret_cast<const h8*>(pr);
            aq[5] = *reinterpret_cast<const h8*>(pr + 32);
        }

        f32x4 o[8] = {};
        float m_i[4] = {-1e30f, -1e30f, -1e30f, -1e30f};
        float l_i[4] = {0.f, 0.f, 0.f, 0.f};

        const int nkb = tile + 1;
        for (int kb64 = 0; kb64 < nkb; kb64++) {
            const int kb = kb64 * 64;
            __syncthreads();
            // ---- cooperative stage ----
            #pragma unroll
            for (int j = 0; j < 4; j++) {            // K nope 16KB
                const int r = (w * 4 + j) * 4 + l4;
                const int cp = l15;
                const int cl = (cp & 8) | ((cp & 7) ^ (r & 7));
                gload_lds16(kn + (bT + kb + r) * 2048 + h * 128 + cl * 8,
                            &Ks_n[(w * 4 + j) * 512]);
            }
            #pragma unroll
            for (int j = 0; j < 2; j++) {            // K rope 8KB
                const int r = (w * 2 + j) * 8 + (lane >> 3);
                const int cl = (lane & 7) ^ (r & 7);
                gload_lds16(kr16 + (bT + kb + r) * 64 + cl * 8,
                            &Ks_r[(w * 2 + j) * 512]);
            }
            #pragma unroll
            for (int j = 0; j < 4; j++) {            // V^T 16KB
                const int d = (w * 4 + j) * 8 + (lane >> 3);
                const int cl = (lane & 7) ^ (d & 7);
                gload_lds16(vt_h + (size_t)d * Tn + kb + cl * 8,
                            &Vs[(w * 4 + j) * 512]);
            }
            __syncthreads();

            if (kb <= qw + 15) {
                // ---- QK^T ----
                f32x4 s[4] = {};
                #pragma unroll
                for (int c = 0; c < 4; c++) {
                    const int kr = c * 16 + l15;
                    const int sw = (kr & 7) << 4;
                    const char* kbase = (const char*)Ks_n + kr * 256;
                    #pragma unroll
                    for (int f = 0; f < 4; f++)
                        s[c] = mfma16(aq[f], *(const h8*)(kbase + ((f * 64 + l4 * 16) ^ sw)), s[c]);
                    const char* rbase = (const char*)Ks_r + kr * 128;
                    s[c] = mfma16(aq[4], *(const h8*)(rbase + ((l4 * 16) ^ sw)), s[c]);
                    s[c] = mfma16(aq[5], *(const h8*)(rbase + ((64 + l4 * 16) ^ sw)), s[c]);
                }
                // ---- online softmax ----
                const float scl = 0.07216878364870323f;  // 1/sqrt(192)
                float al[4];
                #pragma unroll
                for (int r = 0; r < 4; r++) {
                    const int qrow = qw + l4 * 4 + r;
                    float a[4];
                    #pragma unroll
                    for (int c = 0; c < 4; c++)
                        a[c] = (kb + c * 16 + l15 <= qrow) ? s[c][r] * scl : -1e30f;
                    float mx = fmaxf(fmaxf(a[0], a[1]), fmaxf(a[2], a[3]));
                    #pragma unroll
                    for (int sh = 1; sh < 16; sh <<= 1) mx = fmaxf(mx, __shfl_xor(mx, sh));
                    const float mn = fmaxf(m_i[r], mx);
                    const float alpha = __expf(m_i[r] - mn);
                    m_i[r] = mn;
                    float rs = 0.f;
                    #pragma unroll
                    for (int c = 0; c < 4; c++) {
                        const float e = __expf(a[c] - mn);
                        rs += e;
                        Ps[w][l4 * 4 + r][c * 16 + l15] = (HT)e;
                    }
                    #pragma unroll
                    for (int sh = 1; sh < 16; sh <<= 1) rs += __shfl_xor(rs, sh);
                    l_i[r] = l_i[r] * alpha + rs;
                    al[r] = alpha;
                }
                #pragma unroll
                for (int g = 0; g < 8; g++)
                    #pragma unroll
                    for (int r = 0; r < 4; r++) o[g][r] *= al[r];

                const h8 ap0 = *reinterpret_cast<const h8*>(&Ps[w][l15][l4 * 8]);
                const h8 ap1 = *reinterpret_cast<const h8*>(&Ps[w][l15][32 + l4 * 8]);

                // ---- O += P @ V ----
                #pragma unroll
                for (int g = 0; g < 8; g++) {
                    const int d = g * 16 + l15;
                    const int sw = (d & 7) << 4;
                    const char* vbase = (const char*)Vs + d * 128;
                    h8 v0 = *(const h8*)(vbase + ((l4 * 16) ^ sw));
                    h8 v1 = *(const h8*)(vbase + ((64 + l4 * 16) ^ sw));
                    o[g] = mfma16(ap0, v0, o[g]);
                    o[g] = mfma16(ap1, v1, o[g]);
                }
            }
        }

        const size_t orow = bT + qw + l4 * 4;
        #pragma unroll
        for (int r = 0; r < 4; r++) {
            const float inv = 1.0f / l_i[r];
            HT* dst = ao + (orow + r) * 2048 + h * 128 + l15;
            #pragma unroll
            for (int g = 0; g < 8; g++) dst[g * 16] = (HT)(o[g][r] * inv);
        }
    }
}

// ---------------------------------------------------------------------------
extern "C" void kernel_launch(void* const* d_in, const int* in_sizes, int n_in,
                              void* d_out, int out_size, void* d_ws, size_t ws_size,
                              hipStream_t stream)
{
    const float* x     = (const float*)d_in[0];
    const float* w_cq  = (const float*)d_in[1];
    const float* g_q   = (const float*)d_in[2];
    const float* w_ckv = (const float*)d_in[3];
    const float* g_kv  = (const float*)d_in[4];
    const float* w_dqn = (const float*)d_in[5];
    const float* w_dqr = (const float*)d_in[6];
    const float* w_dkn = (const float*)d_in[7];
    const float* w_dv  = (const float*)d_in[8];
    const float* w_kr  = (const float*)d_in[9];
    const float* w_out = (const float*)d_in[10];

    char* ws = (char*)d_ws;
    // weight region (first 4 dead after up-projections -> vt aliases them)
    HT* cqT   = (HT*)(ws + 0);           // [1536][2048]  6,291,456
    HT* ckvT  = (HT*)(ws + 6291456);     // [512][2048]   2,097,152
    HT* dqnT  = (HT*)(ws + 8388608);     // [2048][1536]  6,291,456
    HT* dqrT  = (HT*)(ws + 14680064);    // [1024][1536]  3,145,728
    HT* dknT  = (HT*)(ws + 17825792);    // [2048][512]   2,097,152
    HT* dvT   = (HT*)(ws + 19922944);    // [2048][512]   2,097,152
    HT* outT  = (HT*)(ws + 22020096);    // [2048][2048]  8,388,608
    HT* krT   = (HT*)(ws + 30408704);    // [64][2048]      262,144
    HT* cq    = (HT*)(ws + 30670848);    // [4096][1536] 12,582,912
    HT* ckv   = (HT*)(ws + 43253760);    // [4096][512]   4,194,304
    HT* qn    = (HT*)(ws + 47448064);    // [4096][2048] 16,777,216  (-> ao)
    HT* qr    = (HT*)(ws + 64225280);    // [4096][1024]  8,388,608
    HT* kn    = (HT*)(ws + 72613888);    // [4096][2048] 16,777,216
    HT* kr16  = (HT*)(ws + 89391104);    // [4096][64]      524,288
    float2* cstab = (float2*)(ws + 89915392); // [2048][32]  524,288
    HT* vt    = (HT*)(ws + 0);           // [2][16][128][2048] 16,777,216 (alias)
    HT* ao    = qn;
    HT* x16   = (HT*)(ws + 90439680);    // [4096][2048] 16,777,216 (optional)
    const bool bigA = ws_size >= 107216896ull;

    float* out_o = (float*)d_out;
    float* out_k = out_o + (size_t)BT * Dm;
    float* out_v = out_k + (size_t)2 * Hh * Tn * 192;

    const dim3 blk(256);

    cstab_kernel<<<dim3(256), blk, 0, stream>>>(cstab);
    // weight transposes: src [K][N] -> dst [N][K]
    wtrans_kernel<<<dim3(QRc/64,  Dm/64), blk, 0, stream>>>(w_cq,  cqT,  Dm,  QRc);
    wtrans_kernel<<<dim3(KVRc/64, Dm/64), blk, 0, stream>>>(w_ckv, ckvT, Dm,  KVRc);
    wtrans_kernel<<<dim3(Dm/64, QRc/64),  blk, 0, stream>>>(w_dqn, dqnT, QRc, Dm);
    wtrans_kernel<<<dim3((Hh*RDc)/64, QRc/64), blk, 0, stream>>>(w_dqr, dqrT, QRc, Hh*RDc);
    wtrans_kernel<<<dim3(Dm/64, KVRc/64), blk, 0, stream>>>(w_dkn, dknT, KVRc, Dm);
    wtrans_kernel<<<dim3(Dm/64, KVRc/64), blk, 0, stream>>>(w_dv,  dvT,  KVRc, Dm);
    wtrans_kernel<<<dim3(Dm/64, Dm/64),   blk, 0, stream>>>(w_out, outT, Hh*VDc, Dm);
    wtrans_kernel<<<dim3(RDc/64, Dm/64),  blk, 0, stream>>>(w_kr,  krT,  Dm,  RDc);

    // latent projections
    if (bigA) {
        convx_kernel<<<dim3(4096), blk, 0, stream>>>(x, x16);
        gemm16<false,0,HT><<<dim3(QRc/128,  BT/128), blk, 0, stream>>>(x16, cqT,  cq,  QRc,  Dm, nullptr, nullptr, nullptr);
        gemm16<false,0,HT><<<dim3(KVRc/128, BT/128), blk, 0, stream>>>(x16, ckvT, ckv, KVRc, Dm, nullptr, nullptr, nullptr);
    } else {
        gemm16<true,0,HT><<<dim3(QRc/128,  BT/128), blk, 0, stream>>>(x, cqT,  cq,  QRc,  Dm, nullptr, nullptr, nullptr);
        gemm16<true,0,HT><<<dim3(KVRc/128, BT/128), blk, 0, stream>>>(x, ckvT, ckv, KVRc, Dm, nullptr, nullptr, nullptr);
    }
    krgemm_kernel<<<dim3(BT/128), blk, 0, stream>>>(x, krT, kr16, cstab);
    kropebc_kernel<<<dim3(256), blk, 0, stream>>>(kr16, out_k);

    rmsnorm_kernel<<<dim3(BT), blk, 0, stream>>>(cq,  g_q,  QRc);
    rmsnorm_kernel<<<dim3(BT), blk, 0, stream>>>(ckv, g_kv, KVRc);

    // up-projections (fused epilogues)
    gemm16<false,0,HT><<<dim3(Dm/128, BT/128), blk, 0, stream>>>(cq, dqnT, qn, Dm, QRc, nullptr, nullptr, nullptr);
    gemm16<false,1,HT><<<dim3((Hh*RDc)/128, BT/128), blk, 0, stream>>>(cq, dqrT, qr, Hh*RDc, QRc, nullptr, nullptr, cstab);
    gemm16<false,2,HT><<<dim3(Dm/128, BT/128), blk, 0, stream>>>(ckv, dknT, kn, Dm, KVRc, nullptr, out_k, nullptr);
    gemm16<false,3,HT><<<dim3(Dm/128, BT/128), blk, 0, stream>>>(ckv, dvT, (HT*)nullptr, Dm, KVRc, vt, out_v, nullptr);

    // attention
    attn3_kernel<<<dim3(512), blk, 0, stream>>>(qn, qr, kn, kr16, vt, ao);

    // output projection
    gemm16<false,0,float><<<dim3(Dm/128, BT/128), blk, 0, stream>>>(ao, outT, out_o, Dm, Hh*VDc, nullptr, nullptr, nullptr);
}

// Round 4
// 438.508 us; speedup vs baseline: 3.1230x; 1.1634x over previous
//
#include <hip/hip_runtime.h>
#include <cstdint>
#include <cstddef>

typedef _Float16 HT;
typedef _Float16 h8 __attribute__((ext_vector_type(8)));
typedef _Float16 h4 __attribute__((ext_vector_type(4)));
typedef float f32x4 __attribute__((ext_vector_type(4)));

constexpr int Tn  = 2048;
constexpr int Dm  = 2048;
constexpr int Hh  = 16;
constexpr int RDc = 64;
constexpr int QRc = 1536;
constexpr int KVRc= 512;
constexpr int BT  = 4096;

#define VWAIT(N) asm volatile("s_waitcnt vmcnt(" #N ")" ::: "memory")
#define SBAR()   __builtin_amdgcn_s_barrier()

__device__ __forceinline__ f32x4 mfma16(h8 a, h8 b, f32x4 c) {
    return __builtin_amdgcn_mfma_f32_16x16x32_f16(a, b, c, 0, 0, 0);
}
__device__ __forceinline__ void gload_lds16(const void* g, void* l) {
    __builtin_amdgcn_global_load_lds(
        (const __attribute__((address_space(1))) unsigned int*)g,
        (__attribute__((address_space(3))) unsigned int*)l, 16, 0, 0);
}

// ---------------------------------------------------------------------------
// cos/sin table: cstab[t*32+i] = (cos, sin) of t * 10000^(-i/32)
// ---------------------------------------------------------------------------
__global__ __launch_bounds__(256)
void cstab_kernel(float2* __restrict__ cs)
{
    const int idx = blockIdx.x * 256 + threadIdx.x;   // 65536
    const int t = idx >> 5, i = idx & 31;
    const float ang = (float)t * exp2f(-(float)i * (13.287712379549449f / 32.f));
    cs[idx] = make_float2(cosf(ang), sinf(ang));
}

// ---------------------------------------------------------------------------
// Weight transpose+convert: src fp32 [K][N] -> dst fp16 [N][K]
// ---------------------------------------------------------------------------
__global__ __launch_bounds__(256)
void wtrans_kernel(const float* __restrict__ src, HT* __restrict__ dst,
                   int K, int N)
{
    __shared__ float Ts[64][65];
    const int k0 = blockIdx.y * 64, n0 = blockIdx.x * 64;
    const int tid = threadIdx.x;
    {
        const int r = tid >> 2, c0 = (tid & 3) * 16;
        const float* s = src + (size_t)(k0 + r) * N + n0 + c0;
        #pragma unroll
        for (int j = 0; j < 4; j++)
            *reinterpret_cast<f32x4*>(&Ts[r][c0 + j * 4]) = *reinterpret_cast<const f32x4*>(s + j * 4);
    }
    __syncthreads();
    {
        const int c = tid >> 2, kq = (tid & 3) * 16;
        h8 o0, o1;
        #pragma unroll
        for (int j = 0; j < 8; j++) { o0[j] = (HT)Ts[kq + j][c]; o1[j] = (HT)Ts[kq + 8 + j][c]; }
        HT* d = dst + (size_t)(n0 + c) * K + k0 + kq;
        *reinterpret_cast<h8*>(d)     = o0;
        *reinterpret_cast<h8*>(d + 8) = o1;
    }
}

// ---------------------------------------------------------------------------
__global__ __launch_bounds__(256)
void convx_kernel(const float* __restrict__ x, HT* __restrict__ x16)
{
    const size_t i = ((size_t)blockIdx.x * 256 + threadIdx.x) * 8;
    f32x4 a = *reinterpret_cast<const f32x4*>(x + i);
    f32x4 b = *reinterpret_cast<const f32x4*>(x + i + 4);
    h8 v;
    #pragma unroll
    for (int j = 0; j < 4; j++) { v[j] = (HT)a[j]; v[4 + j] = (HT)b[j]; }
    *reinterpret_cast<h8*>(x16 + i) = v;
}

// ---------------------------------------------------------------------------
// Double-buffered m97-style GEMM, 128x128 tile, BK=32, counted vmcnt.
// A fp16 [M][K], Bt fp16 [N][K]. EPI: 0=latent(cq|ckv|kr16-rope)
// 1=Q(qn|qr-rope) 2=KV(kn+out_k | vt+out_v) 3=OUT(fp32)
// ---------------------------------------------------------------------------
template<int EPI>
__global__ __launch_bounds__(256)
void gemm16d(const HT* __restrict__ A, const HT* __restrict__ Bt, const int K,
             HT* __restrict__ o1, HT* __restrict__ o2, HT* __restrict__ o3,
             float* __restrict__ f1, float* __restrict__ f2,
             const float2* __restrict__ cstab)
{
    __shared__ HT As[2][4096];
    __shared__ HT Bs[2][4096];

    const int tid  = threadIdx.x;
    const int lane = tid & 63;
    const int l15  = lane & 15, l4 = lane >> 4;
    const int w    = tid >> 6;
    const int wr   = w >> 1, wc = w & 1;
    const int m0   = blockIdx.y * 128;
    const int n0   = blockIdx.x * 128;

    f32x4 acc[4][4] = {};
    const int nk = K >> 5;

#define GSTAGE(as_, bs_, kt_) do {                                             \
    _Pragma("unroll")                                                          \
    for (int i_ = 0; i_ < 2; i_++) {                                           \
        const int row_ = (w * 2 + i_) * 16 + (lane >> 2);                      \
        gload_lds16(A  + (size_t)(m0 + row_) * K + (kt_) + (lane & 3) * 8,     \
                    (as_) + (w * 2 + i_) * 512);                               \
        gload_lds16(Bt + (size_t)(n0 + row_) * K + (kt_) + (lane & 3) * 8,     \
                    (bs_) + (w * 2 + i_) * 512);                               \
    } } while (0)

    GSTAGE(As[0], Bs[0], 0);

    for (int kt = 0; kt < nk; kt++) {
        HT* as = As[kt & 1];
        HT* bs = Bs[kt & 1];
        if (kt + 1 < nk) {
            GSTAGE(As[(kt + 1) & 1], Bs[(kt + 1) & 1], (kt + 1) * 32);
            VWAIT(4);
        } else {
            VWAIT(0);
        }
        SBAR();

        h8 af[4], bf[4];
        #pragma unroll
        for (int f = 0; f < 4; f++)
            af[f] = *reinterpret_cast<const h8*>(&as[(wr * 64 + f * 16 + l15) * 32 + l4 * 8]);
        #pragma unroll
        for (int g = 0; g < 4; g++)
            bf[g] = *reinterpret_cast<const h8*>(&bs[(wc * 64 + g * 16 + l15) * 32 + l4 * 8]);
        #pragma unroll
        for (int f = 0; f < 4; f++)
            #pragma unroll
            for (int g = 0; g < 4; g++)
                acc[f][g] = mfma16(af[f], bf[g], acc[f][g]);
        SBAR();
    }
#undef GSTAGE

    #pragma unroll
    for (int f = 0; f < 4; f++) {
        #pragma unroll
        for (int g = 0; g < 4; g++) {
            const int row = m0 + wr * 64 + f * 16 + l4 * 4;
            const int col = n0 + wc * 64 + g * 16 + l15;
            if constexpr (EPI == 3) {
                #pragma unroll
                for (int r = 0; r < 4; r++)
                    f1[(size_t)(row + r) * 2048 + col] = acc[f][g][r];
            } else if constexpr (EPI == 0) {
                if (col < 1536) {
                    #pragma unroll
                    for (int r = 0; r < 4; r++)
                        o1[(size_t)(row + r) * 1536 + col] = (HT)acc[f][g][r];
                } else if (col < 2048) {
                    #pragma unroll
                    for (int r = 0; r < 4; r++)
                        o2[(size_t)(row + r) * 512 + (col - 1536)] = (HT)acc[f][g][r];
                } else if (col < 2112) {
                    const int cc = col - 2048;
                    const int i = cc >> 1;
                    const bool odd = cc & 1;
                    #pragma unroll
                    for (int r = 0; r < 4; r++) {
                        const int t = (row + r) & (Tn - 1);
                        const float2 cs = cstab[t * 32 + i];
                        const float v = acc[f][g][r];
                        const float p = __shfl_xor(v, 1);
                        const float ov = odd ? p * cs.y + v * cs.x : v * cs.x - p * cs.y;
                        o3[(size_t)(row + r) * 64 + cc] = (HT)ov;
                    }
                }
            } else if constexpr (EPI == 1) {
                if (col < 2048) {
                    #pragma unroll
                    for (int r = 0; r < 4; r++)
                        o1[(size_t)(row + r) * 2048 + col] = (HT)acc[f][g][r];
                } else {
                    const int cc = col - 2048;
                    const int i = (cc & 63) >> 1;
                    const bool odd = cc & 1;
                    #pragma unroll
                    for (int r = 0; r < 4; r++) {
                        const int t = (row + r) & (Tn - 1);
                        const float2 cs = cstab[t * 32 + i];
                        const float v = acc[f][g][r];
                        const float p = __shfl_xor(v, 1);
                        const float ov = odd ? p * cs.y + v * cs.x : v * cs.x - p * cs.y;
                        o2[(size_t)(row + r) * 1024 + cc] = (HT)ov;
                    }
                }
            } else {  // EPI == 2
                if (col < 2048) {
                    const int h = col >> 7, d = col & 127;
                    #pragma unroll
                    for (int r = 0; r < 4; r++) {
                        const int rw = row + r;
                        const int b = rw >> 11, t = rw & (Tn - 1);
                        o1[(size_t)rw * 2048 + col] = (HT)acc[f][g][r];
                        f1[((size_t)(b * Hh + h) * Tn + t) * 192 + d] = acc[f][g][r];
                    }
                } else {
                    const int c2 = col - 2048;
                    const int h = c2 >> 7, d = c2 & 127;
                    const int b = row >> 11, t0 = row & (Tn - 1);
                    h4 pk;
                    #pragma unroll
                    for (int r = 0; r < 4; r++) {
                        f2[((size_t)(b * Hh + h) * Tn + t0 + r) * 128 + d] = acc[f][g][r];
                        pk[r] = (HT)acc[f][g][r];
                    }
                    *reinterpret_cast<h4*>(&o3[((size_t)(b * Hh + h) * 128 + d) * Tn + t0]) = pk;
                }
            }
        }
    }
}

// ---------------------------------------------------------------------------
// broadcast rope slice of out_k across 16 heads (fp32)
// ---------------------------------------------------------------------------
__global__ __launch_bounds__(256)
void kropebc_kernel(const HT* __restrict__ kr16, float* __restrict__ out_k)
{
    const int idx = blockIdx.x * 256 + threadIdx.x;    // 2*2048*16
    const int j4 = (idx & 15) * 4;
    const int t  = (idx >> 4) & (Tn - 1);
    const int b  = idx >> 15;
    h4 v = *reinterpret_cast<const h4*>(&kr16[((size_t)(b * Tn + t)) * 64 + j4]);
    f32x4 f;
    #pragma unroll
    for (int r = 0; r < 4; r++) f[r] = (float)v[r];
    #pragma unroll
    for (int h = 0; h < Hh; h++)
        *reinterpret_cast<f32x4*>(&out_k[((size_t)(b * Hh + h) * Tn + t) * 192 + 128 + j4]) = f;
}

// ---------------------------------------------------------------------------
__global__ __launch_bounds__(256)
void rmsnorm_kernel(HT* __restrict__ X, const float* __restrict__ g, int N)
{
    const int row = blockIdx.x;
    HT* x = X + (size_t)row * N;
    float ss = 0.f;
    for (int i = threadIdx.x * 8; i < N; i += 2048) {
        h8 v = *reinterpret_cast<const h8*>(&x[i]);
        #pragma unroll
        for (int j = 0; j < 8; j++) { float f = (float)v[j]; ss += f * f; }
    }
    #pragma unroll
    for (int sh = 32; sh >= 1; sh >>= 1) ss += __shfl_xor(ss, sh);
    __shared__ float red[4];
    if ((threadIdx.x & 63) == 0) red[threadIdx.x >> 6] = ss;
    __syncthreads();
    const float tot = red[0] + red[1] + red[2] + red[3];
    const float scale = rsqrtf(tot / (float)N + 1e-6f);
    for (int i = threadIdx.x * 8; i < N; i += 2048) {
        h8 v = *reinterpret_cast<const h8*>(&x[i]);
        f32x4 g0 = *reinterpret_cast<const f32x4*>(&g[i]);
        f32x4 g1 = *reinterpret_cast<const f32x4*>(&g[i + 4]);
        #pragma unroll
        for (int j = 0; j < 4; j++) { v[j]   = (HT)((float)v[j]   * scale * g0[j]);
                                      v[4+j] = (HT)((float)v[4+j] * scale * g1[j]); }
        *reinterpret_cast<h8*>(&x[i]) = v;
    }
}

// ---------------------------------------------------------------------------
// Flash attention v4: dbuf-K staging w/ counted vmcnt, exp2-domain softmax,
// defer-max. Grid 512 flat -> (tl, h, b) XCD-chunked; mirrored supertiles.
// ---------------------------------------------------------------------------
__global__ __launch_bounds__(256)
void attn4_kernel(const HT* __restrict__ qn, const HT* __restrict__ qr,
                  const HT* __restrict__ kn, const HT* __restrict__ kr16,
                  const HT* __restrict__ vt, HT* __restrict__ ao)
{
    __shared__ HT KsN[2][64 * 128];
    __shared__ HT KsR[2][64 * 64];
    __shared__ HT Vs[128 * 64];
    __shared__ HT Ps[4][16][72];

    const int tid  = threadIdx.x;
    const int lane = tid & 63;
    const int l15  = lane & 15, l4 = lane >> 4;
    const int w    = tid >> 6;

    const int bid = blockIdx.x;                    // 512
    const int wid = (bid & 7) * 64 + (bid >> 3);   // XCD-chunked remap
    const int tl  = wid & 15;
    const int h   = (wid >> 4) & 15;
    const int b   = wid >> 8;

    const size_t bT = (size_t)b * Tn;
    const HT* vt_h = vt + ((size_t)(b * Hh + h) * 128) * Tn;
    const float SCL2 = 0.07216878364870323f * 1.4426950408889634f; // 1/sqrt(192)*log2e

#define STAGEK(buf_, kb_) do {                                                  \
    _Pragma("unroll")                                                           \
    for (int j_ = 0; j_ < 4; j_++) {                                            \
        const int r_ = (w * 4 + j_) * 4 + l4;                                   \
        const int cl_ = (l15 & 8) | ((l15 & 7) ^ (r_ & 7));                     \
        gload_lds16(kn + (bT + (kb_) + r_) * 2048 + h * 128 + cl_ * 8,          \
                    &KsN[buf_][(w * 4 + j_) * 512]);                            \
    }                                                                           \
    _Pragma("unroll")                                                           \
    for (int j_ = 0; j_ < 2; j_++) {                                            \
        const int r_ = (w * 2 + j_) * 8 + (lane >> 3);                          \
        const int cl_ = (lane & 7) ^ (r_ & 7);                                  \
        gload_lds16(kr16 + (bT + (kb_) + r_) * 64 + cl_ * 8,                    \
                    &KsR[buf_][(w * 2 + j_) * 512]);                            \
    } } while (0)

#define STAGEV(kb_) do {                                                        \
    _Pragma("unroll")                                                           \
    for (int j_ = 0; j_ < 4; j_++) {                                            \
        const int d_ = (w * 4 + j_) * 8 + (lane >> 3);                          \
        const int cl_ = (lane & 7) ^ (d_ & 7);                                  \
        gload_lds16(vt_h + (size_t)d_ * Tn + (kb_) + cl_ * 8,                   \
                    &Vs[(w * 4 + j_) * 512]);                                   \
    } } while (0)

    for (int ph = 0; ph < 2; ph++) {
        const int tile = ph ? (31 - tl) : tl;
        const int qw = tile * 64 + 16 * w;

        // hoist Q fragments, pre-scaled into exp2 domain
        h8 aq[6];
        {
            const size_t rq = bT + qw + l15;
            const HT* pn = qn + rq * 2048 + h * 128 + l4 * 8;
            #pragma unroll
            for (int f = 0; f < 4; f++) aq[f] = *reinterpret_cast<const h8*>(pn + f * 32);
            const HT* pr = qr + rq * 1024 + h * 64 + l4 * 8;
            aq[4] = *reinterpret_cast<const h8*>(pr);
            aq[5] = *reinterpret_cast<const h8*>(pr + 32);
            const HT sc = (HT)SCL2;
            #pragma unroll
            for (int f = 0; f < 6; f++) aq[f] = aq[f] * sc;
        }

        f32x4 o[8] = {};
        float m_i[4] = {-1e30f, -1e30f, -1e30f, -1e30f};
        float l_i[4] = {0.f, 0.f, 0.f, 0.f};

        VWAIT(0);                         // clear queue (aq loads / prior stores)
        const int nkb = tile + 1;
        STAGEK(0, 0);

        for (int t = 0; t < nkb; t++) {
            const int kb = t * 64;
            const int cur = t & 1;
            const bool hn = (t + 1 < nkb);
            SBAR();                       // Vs safe to overwrite
            STAGEV(kb);
            if (hn) { STAGEK(cur ^ 1, kb + 64); VWAIT(10); }
            else    { VWAIT(4); }
            SBAR();                       // K(t) visible to all waves
            const bool compute = (kb <= qw + 15);
            float a[4][4];
            if (compute) {
                const HT* ksn = KsN[cur];
                const HT* ksr = KsR[cur];
                f32x4 s[4] = {};
                #pragma unroll
                for (int c = 0; c < 4; c++) {
                    const int kr = c * 16 + l15;
                    const int sw = (kr & 7) << 4;
                    const char* kbase = (const char*)ksn + kr * 256;
                    #pragma unroll
                    for (int f = 0; f < 4; f++)
                        s[c] = mfma16(aq[f], *(const h8*)(kbase + ((f * 64 + l4 * 16) ^ sw)), s[c]);
                    const char* rbase = (const char*)ksr + kr * 128;
                    s[c] = mfma16(aq[4], *(const h8*)(rbase + ((l4 * 16) ^ sw)), s[c]);
                    s[c] = mfma16(aq[5], *(const h8*)(rbase + ((64 + l4 * 16) ^ sw)), s[c]);
                }
                // ---- online softmax (exp2 domain) ----
                float mxv[4];
                #pragma unroll
                for (int r = 0; r < 4; r++) {
                    const int qrow = qw + l4 * 4 + r;
                    #pragma unroll
                    for (int c = 0; c < 4; c++)
                        a[r][c] = (kb + c * 16 + l15 <= qrow) ? s[c][r] : -1e30f;
                    float mx = fmaxf(fmaxf(a[r][0], a[r][1]), fmaxf(a[r][2], a[r][3]));
                    #pragma unroll
                    for (int sh = 1; sh < 16; sh <<= 1) mx = fmaxf(mx, __shfl_xor(mx, sh));
                    mxv[r] = mx;
                }
                const bool ok = (mxv[0] <= m_i[0] + 11.f) && (mxv[1] <= m_i[1] + 11.f) &&
                                (mxv[2] <= m_i[2] + 11.f) && (mxv[3] <= m_i[3] + 11.f);
                if (__all(ok)) {
                    #pragma unroll
                    for (int r = 0; r < 4; r++) {
                        float rs = 0.f;
                        #pragma unroll
                        for (int c = 0; c < 4; c++) {
                            const float e = __builtin_exp2f(a[r][c] - m_i[r]);
                            rs += e;
                            Ps[w][l4 * 4 + r][c * 16 + l15] = (HT)e;
                        }
                        #pragma unroll
                        for (int sh = 1; sh < 16; sh <<= 1) rs += __shfl_xor(rs, sh);
                        l_i[r] += rs;
                    }
                } else {
                    float al[4];
                    #pragma unroll
                    for (int r = 0; r < 4; r++) {
                        const float mn = fmaxf(m_i[r], mxv[r]);
                        al[r] = __builtin_exp2f(m_i[r] - mn);
                        m_i[r] = mn;
                        float rs = 0.f;
                        #pragma unroll
                        for (int c = 0; c < 4; c++) {
                            const float e = __builtin_exp2f(a[r][c] - mn);
                            rs += e;
                            Ps[w][l4 * 4 + r][c * 16 + l15] = (HT)e;
                        }
                        #pragma unroll
                        for (int sh = 1; sh < 16; sh <<= 1) rs += __shfl_xor(rs, sh);
                        l_i[r] = l_i[r] * al[r] + rs;
                    }
                    #pragma unroll
                    for (int g = 0; g < 8; g++)
                        #pragma unroll
                        for (int r = 0; r < 4; r++) o[g][r] *= al[r];
                }
            }
            if (hn) { VWAIT(6); } else { VWAIT(0); }
            SBAR();                       // V(t) visible to all waves
            if (compute) {
                const h8 ap0 = *reinterpret_cast<const h8*>(&Ps[w][l15][l4 * 8]);
                const h8 ap1 = *reinterpret_cast<const h8*>(&Ps[w][l15][32 + l4 * 8]);
                #pragma unroll
                for (int g = 0; g < 8; g++) {
                    const int d = g * 16 + l15;
                    const int sw = (d & 7) << 4;
                    const char* vbase = (const char*)Vs + d * 128;
                    h8 v0 = *(const h8*)(vbase + ((l4 * 16) ^ sw));
                    h8 v1 = *(const h8*)(vbase + ((64 + l4 * 16) ^ sw));
                    o[g] = mfma16(ap0, v0, o[g]);
                    o[g] = mfma16(ap1, v1, o[g]);
                }
            }
        }

        const size_t orow = bT + qw + l4 * 4;
        #pragma unroll
        for (int r = 0; r < 4; r++) {
            const float inv = 1.0f / l_i[r];
            HT* dst = ao + (orow + r) * 2048 + h * 128 + l15;
            #pragma unroll
            for (int g = 0; g < 8; g++) dst[g * 16] = (HT)(o[g][r] * inv);
        }
    }
#undef STAGEK
#undef STAGEV
}

// ---------------------------------------------------------------------------
extern "C" void kernel_launch(void* const* d_in, const int* in_sizes, int n_in,
                              void* d_out, int out_size, void* d_ws, size_t ws_size,
                              hipStream_t stream)
{
    const float* x     = (const float*)d_in[0];
    const float* w_cq  = (const float*)d_in[1];
    const float* g_q   = (const float*)d_in[2];
    const float* w_ckv = (const float*)d_in[3];
    const float* g_kv  = (const float*)d_in[4];
    const float* w_dqn = (const float*)d_in[5];
    const float* w_dqr = (const float*)d_in[6];
    const float* w_dkn = (const float*)d_in[7];
    const float* w_dv  = (const float*)d_in[8];
    const float* w_kr  = (const float*)d_in[9];
    const float* w_out = (const float*)d_in[10];

    char* ws = (char*)d_ws;
    // weight region (dead after their GEMM -> vt aliases it)
    HT* cqT   = (HT*)(ws + 0);           // [1536][2048]  6,291,456
    HT* ckvT  = (HT*)(ws + 6291456);     // [512][2048]   2,097,152
    HT* krT   = (HT*)(ws + 8388608);     // [64][2048]      262,144
    //  pad region [8650752, 8912896) read as garbage B rows (never written out)
    HT* dqnT  = (HT*)(ws + 8912896);     // [2048][1536]  6,291,456
    HT* dqrT  = (HT*)(ws + 15204352);    // [1024][1536]  3,145,728
    HT* dknT  = (HT*)(ws + 18350080);    // [2048][512]   2,097,152
    HT* dvT   = (HT*)(ws + 20447232);    // [2048][512]   2,097,152
    HT* outT  = (HT*)(ws + 22544384);    // [2048][2048]  8,388,608
    HT* cq    = (HT*)(ws + 30932992);    // [4096][1536] 12,582,912
    HT* ckv   = (HT*)(ws + 43515904);    // [4096][512]   4,194,304
    HT* qn    = (HT*)(ws + 47710208);    // [4096][2048] 16,777,216 (x16/ao alias)
    HT* qr    = (HT*)(ws + 64487424);    // [4096][1024]  8,388,608
    HT* kn    = (HT*)(ws + 72876032);    // [4096][2048] 16,777,216
    HT* kr16  = (HT*)(ws + 89653248);    // [4096][64]      524,288  (end 90,177,536)
    HT* vt    = (HT*)(ws + 0);           // [2][16][128][2048] 16,777,216 (alias)
    HT* x16   = qn;                      // x16 dead before qn written
    HT* ao    = qn;                      // attn reads/writes same (row,h) slice

    float* out_o = (float*)d_out;
    float* out_k = out_o + (size_t)BT * Dm;
    float* out_v = out_k + (size_t)2 * Hh * Tn * 192;
    float2* cstab = (float2*)out_v;      // stashed in out_v head; KV GEMM
                                         // overwrites it AFTER last use (Q GEMM)

    const dim3 blk(256);

    cstab_kernel<<<dim3(256), blk, 0, stream>>>(cstab);
    // weight transposes: src [K][N] -> dst [N][K]
    wtrans_kernel<<<dim3(QRc/64,  Dm/64), blk, 0, stream>>>(w_cq,  cqT,  Dm,  QRc);
    wtrans_kernel<<<dim3(KVRc/64, Dm/64), blk, 0, stream>>>(w_ckv, ckvT, Dm,  KVRc);
    wtrans_kernel<<<dim3(RDc/64,  Dm/64), blk, 0, stream>>>(w_kr,  krT,  Dm,  RDc);
    wtrans_kernel<<<dim3(Dm/64, QRc/64),  blk, 0, stream>>>(w_dqn, dqnT, QRc, Dm);
    wtrans_kernel<<<dim3((Hh*RDc)/64, QRc/64), blk, 0, stream>>>(w_dqr, dqrT, QRc, Hh*RDc);
    wtrans_kernel<<<dim3(Dm/64, KVRc/64), blk, 0, stream>>>(w_dkn, dknT, KVRc, Dm);
    wtrans_kernel<<<dim3(Dm/64, KVRc/64), blk, 0, stream>>>(w_dv,  dvT,  KVRc, Dm);
    wtrans_kernel<<<dim3(Dm/64, Dm/64),   blk, 0, stream>>>(w_out, outT, Dm,  Dm);

    convx_kernel<<<dim3(4096), blk, 0, stream>>>(x, x16);

    // fused latent GEMM: N=2176 (cq | ckv | kr16-rope | pad)
    gemm16d<0><<<dim3(17, BT/128), blk, 0, stream>>>(x16, cqT, Dm,
        cq, ckv, kr16, nullptr, nullptr, cstab);
    kropebc_kernel<<<dim3(256), blk, 0, stream>>>(kr16, out_k);

    rmsnorm_kernel<<<dim3(BT), blk, 0, stream>>>(cq,  g_q,  QRc);
    rmsnorm_kernel<<<dim3(BT), blk, 0, stream>>>(ckv, g_kv, KVRc);

    // fused Q GEMM: N=3072 (qn | qr-rope)  [reads cstab; must precede KV GEMM]
    gemm16d<1><<<dim3(24, BT/128), blk, 0, stream>>>(cq, dqnT, QRc,
        qn, qr, nullptr, nullptr, nullptr, cstab);
    // fused KV GEMM: N=4096 (kn+out_k | vt+out_v)  [overwrites cstab & weight region]
    gemm16d<2><<<dim3(32, BT/128), blk, 0, stream>>>(ckv, dknT, KVRc,
        kn, nullptr, vt, out_k, out_v, nullptr);

    // attention
    attn4_kernel<<<dim3(512), blk, 0, stream>>>(qn, qr, kn, kr16, vt, ao);

    // output projection
    gemm16d<3><<<dim3(16, BT/128), blk, 0, stream>>>(ao, outT, Dm,
        nullptr, nullptr, nullptr, out_o, nullptr, nullptr);
}

// Round 5
// 385.064 us; speedup vs baseline: 3.5565x; 1.1388x over previous
//
#include <hip/hip_runtime.h>
#include <cstdint>
#include <cstddef>

typedef _Float16 HT;
typedef _Float16 h8 __attribute__((ext_vector_type(8)));
typedef _Float16 h4 __attribute__((ext_vector_type(4)));
typedef float f32x4 __attribute__((ext_vector_type(4)));

constexpr int Tn  = 2048;
constexpr int Dm  = 2048;
constexpr int Hh  = 16;
constexpr int RDc = 64;
constexpr int QRc = 1536;
constexpr int KVRc= 512;
constexpr int BT  = 4096;

#define VWAIT(N) asm volatile("s_waitcnt vmcnt(" #N ")" ::: "memory")
#define SBAR()   __builtin_amdgcn_s_barrier()

__device__ __forceinline__ f32x4 mfma16(h8 a, h8 b, f32x4 c) {
    return __builtin_amdgcn_mfma_f32_16x16x32_f16(a, b, c, 0, 0, 0);
}
__device__ __forceinline__ void gload_lds16(const void* g, void* l) {
    __builtin_amdgcn_global_load_lds(
        (const __attribute__((address_space(1))) unsigned int*)g,
        (__attribute__((address_space(3))) unsigned int*)l, 16, 0, 0);
}

// ---------------------------------------------------------------------------
// cos/sin table: cstab[t*32+i] = (cos, sin) of t * 10000^(-i/32)
// ---------------------------------------------------------------------------
__global__ __launch_bounds__(256)
void cstab_kernel(float2* __restrict__ cs)
{
    const int idx = blockIdx.x * 256 + threadIdx.x;   // 65536
    const int t = idx >> 5, i = idx & 31;
    const float ang = (float)t * exp2f(-(float)i * (13.287712379549449f / 32.f));
    cs[idx] = make_float2(cosf(ang), sinf(ang));
}

// ---------------------------------------------------------------------------
// Weight transpose+convert: src fp32 [K][N] -> dst fp16 [N][K]
// ---------------------------------------------------------------------------
__global__ __launch_bounds__(256)
void wtrans_kernel(const float* __restrict__ src, HT* __restrict__ dst,
                   int K, int N)
{
    __shared__ float Ts[64][65];
    const int k0 = blockIdx.y * 64, n0 = blockIdx.x * 64;
    const int tid = threadIdx.x;
    {
        const int r = tid >> 2, c0 = (tid & 3) * 16;
        const float* s = src + (size_t)(k0 + r) * N + n0 + c0;
        #pragma unroll
        for (int j = 0; j < 4; j++)
            *reinterpret_cast<f32x4*>(&Ts[r][c0 + j * 4]) = *reinterpret_cast<const f32x4*>(s + j * 4);
    }
    __syncthreads();
    {
        const int c = tid >> 2, kq = (tid & 3) * 16;
        h8 o0, o1;
        #pragma unroll
        for (int j = 0; j < 8; j++) { o0[j] = (HT)Ts[kq + j][c]; o1[j] = (HT)Ts[kq + 8 + j][c]; }
        HT* d = dst + (size_t)(n0 + c) * K + k0 + kq;
        *reinterpret_cast<h8*>(d)     = o0;
        *reinterpret_cast<h8*>(d + 8) = o1;
    }
}

// ---------------------------------------------------------------------------
__global__ __launch_bounds__(256)
void convx_kernel(const float* __restrict__ x, HT* __restrict__ x16)
{
    const size_t i = ((size_t)blockIdx.x * 256 + threadIdx.x) * 8;
    f32x4 a = *reinterpret_cast<const f32x4*>(x + i);
    f32x4 b = *reinterpret_cast<const f32x4*>(x + i + 4);
    h8 v;
    #pragma unroll
    for (int j = 0; j < 4; j++) { v[j] = (HT)a[j]; v[4 + j] = (HT)b[j]; }
    *reinterpret_cast<h8*>(x16 + i) = v;
}

// ---------------------------------------------------------------------------
// Double-buffered m97-style GEMM, 128x128 tile, BK=32, counted vmcnt.
// A fp16 [M][K], Bt fp16 [N][K]. EPI: 0=latent(cq|ckv|kr16-rope)
// 1=Q(qn|qr-rope) 2=KV(kn+out_k | vt+out_v) 3=OUT(fp32)
// ---------------------------------------------------------------------------
template<int EPI>
__global__ __launch_bounds__(256)
void gemm16d(const HT* __restrict__ A, const HT* __restrict__ Bt, const int K,
             HT* __restrict__ o1, HT* __restrict__ o2, HT* __restrict__ o3,
             float* __restrict__ f1, float* __restrict__ f2,
             const float2* __restrict__ cstab)
{
    __shared__ HT As[2][4096];
    __shared__ HT Bs[2][4096];

    const int tid  = threadIdx.x;
    const int lane = tid & 63;
    const int l15  = lane & 15, l4 = lane >> 4;
    const int w    = tid >> 6;
    const int wr   = w >> 1, wc = w & 1;
    const int m0   = blockIdx.y * 128;
    const int n0   = blockIdx.x * 128;

    f32x4 acc[4][4] = {};
    const int nk = K >> 5;

#define GSTAGE(as_, bs_, kt_) do {                                             \
    _Pragma("unroll")                                                          \
    for (int i_ = 0; i_ < 2; i_++) {                                           \
        const int row_ = (w * 2 + i_) * 16 + (lane >> 2);                      \
        gload_lds16(A  + (size_t)(m0 + row_) * K + (kt_) + (lane & 3) * 8,     \
                    (as_) + (w * 2 + i_) * 512);                               \
        gload_lds16(Bt + (size_t)(n0 + row_) * K + (kt_) + (lane & 3) * 8,     \
                    (bs_) + (w * 2 + i_) * 512);                               \
    } } while (0)

    GSTAGE(As[0], Bs[0], 0);

    for (int kt = 0; kt < nk; kt++) {
        HT* as = As[kt & 1];
        HT* bs = Bs[kt & 1];
        if (kt + 1 < nk) {
            GSTAGE(As[(kt + 1) & 1], Bs[(kt + 1) & 1], (kt + 1) * 32);
            VWAIT(4);
        } else {
            VWAIT(0);
        }
        SBAR();

        h8 af[4], bf[4];
        #pragma unroll
        for (int f = 0; f < 4; f++)
            af[f] = *reinterpret_cast<const h8*>(&as[(wr * 64 + f * 16 + l15) * 32 + l4 * 8]);
        #pragma unroll
        for (int g = 0; g < 4; g++)
            bf[g] = *reinterpret_cast<const h8*>(&bs[(wc * 64 + g * 16 + l15) * 32 + l4 * 8]);
        #pragma unroll
        for (int f = 0; f < 4; f++)
            #pragma unroll
            for (int g = 0; g < 4; g++)
                acc[f][g] = mfma16(af[f], bf[g], acc[f][g]);
        SBAR();
    }
#undef GSTAGE

    #pragma unroll
    for (int f = 0; f < 4; f++) {
        #pragma unroll
        for (int g = 0; g < 4; g++) {
            const int row = m0 + wr * 64 + f * 16 + l4 * 4;
            const int col = n0 + wc * 64 + g * 16 + l15;
            if constexpr (EPI == 3) {
                #pragma unroll
                for (int r = 0; r < 4; r++)
                    f1[(size_t)(row + r) * 2048 + col] = acc[f][g][r];
            } else if constexpr (EPI == 0) {
                if (col < 1536) {
                    #pragma unroll
                    for (int r = 0; r < 4; r++)
                        o1[(size_t)(row + r) * 1536 + col] = (HT)acc[f][g][r];
                } else if (col < 2048) {
                    #pragma unroll
                    for (int r = 0; r < 4; r++)
                        o2[(size_t)(row + r) * 512 + (col - 1536)] = (HT)acc[f][g][r];
                } else if (col < 2112) {
                    const int cc = col - 2048;
                    const int i = cc >> 1;
                    const bool odd = cc & 1;
                    #pragma unroll
                    for (int r = 0; r < 4; r++) {
                        const int t = (row + r) & (Tn - 1);
                        const float2 cs = cstab[t * 32 + i];
                        const float v = acc[f][g][r];
                        const float p = __shfl_xor(v, 1);
                        const float ov = odd ? p * cs.y + v * cs.x : v * cs.x - p * cs.y;
                        o3[(size_t)(row + r) * 64 + cc] = (HT)ov;
                    }
                }
            } else if constexpr (EPI == 1) {
                if (col < 2048) {
                    #pragma unroll
                    for (int r = 0; r < 4; r++)
                        o1[(size_t)(row + r) * 2048 + col] = (HT)acc[f][g][r];
                } else {
                    const int cc = col - 2048;
                    const int i = (cc & 63) >> 1;
                    const bool odd = cc & 1;
                    #pragma unroll
                    for (int r = 0; r < 4; r++) {
                        const int t = (row + r) & (Tn - 1);
                        const float2 cs = cstab[t * 32 + i];
                        const float v = acc[f][g][r];
                        const float p = __shfl_xor(v, 1);
                        const float ov = odd ? p * cs.y + v * cs.x : v * cs.x - p * cs.y;
                        o2[(size_t)(row + r) * 1024 + cc] = (HT)ov;
                    }
                }
            } else {  // EPI == 2
                if (col < 2048) {
                    const int h = col >> 7, d = col & 127;
                    #pragma unroll
                    for (int r = 0; r < 4; r++) {
                        const int rw = row + r;
                        const int b = rw >> 11, t = rw & (Tn - 1);
                        o1[(size_t)rw * 2048 + col] = (HT)acc[f][g][r];
                        f1[((size_t)(b * Hh + h) * Tn + t) * 192 + d] = acc[f][g][r];
                    }
                } else {
                    const int c2 = col - 2048;
                    const int h = c2 >> 7, d = c2 & 127;
                    const int b = row >> 11, t0 = row & (Tn - 1);
                    h4 pk;
                    #pragma unroll
                    for (int r = 0; r < 4; r++) {
                        f2[((size_t)(b * Hh + h) * Tn + t0 + r) * 128 + d] = acc[f][g][r];
                        pk[r] = (HT)acc[f][g][r];
                    }
                    *reinterpret_cast<h4*>(&o3[((size_t)(b * Hh + h) * 128 + d) * Tn + t0]) = pk;
                }
            }
        }
    }
}

// ---------------------------------------------------------------------------
// broadcast rope slice of out_k across 16 heads (fp32)
// ---------------------------------------------------------------------------
__global__ __launch_bounds__(256)
void kropebc_kernel(const HT* __restrict__ kr16, float* __restrict__ out_k)
{
    const int idx = blockIdx.x * 256 + threadIdx.x;    // 2*2048*16
    const int j4 = (idx & 15) * 4;
    const int t  = (idx >> 4) & (Tn - 1);
    const int b  = idx >> 15;
    h4 v = *reinterpret_cast<const h4*>(&kr16[((size_t)(b * Tn + t)) * 64 + j4]);
    f32x4 f;
    #pragma unroll
    for (int r = 0; r < 4; r++) f[r] = (float)v[r];
    #pragma unroll
    for (int h = 0; h < Hh; h++)
        *reinterpret_cast<f32x4*>(&out_k[((size_t)(b * Hh + h) * Tn + t) * 192 + 128 + j4]) = f;
}

// ---------------------------------------------------------------------------
__global__ __launch_bounds__(256)
void rmsnorm_kernel(HT* __restrict__ X, const float* __restrict__ g, int N)
{
    const int row = blockIdx.x;
    HT* x = X + (size_t)row * N;
    float ss = 0.f;
    for (int i = threadIdx.x * 8; i < N; i += 2048) {
        h8 v = *reinterpret_cast<const h8*>(&x[i]);
        #pragma unroll
        for (int j = 0; j < 8; j++) { float f = (float)v[j]; ss += f * f; }
    }
    #pragma unroll
    for (int sh = 32; sh >= 1; sh >>= 1) ss += __shfl_xor(ss, sh);
    __shared__ float red[4];
    if ((threadIdx.x & 63) == 0) red[threadIdx.x >> 6] = ss;
    __syncthreads();
    const float tot = red[0] + red[1] + red[2] + red[3];
    const float scale = rsqrtf(tot / (float)N + 1e-6f);
    for (int i = threadIdx.x * 8; i < N; i += 2048) {
        h8 v = *reinterpret_cast<const h8*>(&x[i]);
        f32x4 g0 = *reinterpret_cast<const f32x4*>(&g[i]);
        f32x4 g1 = *reinterpret_cast<const f32x4*>(&g[i + 4]);
        #pragma unroll
        for (int j = 0; j < 4; j++) { v[j]   = (HT)((float)v[j]   * scale * g0[j]);
                                      v[4+j] = (HT)((float)v[4+j] * scale * g1[j]); }
        *reinterpret_cast<h8*>(&x[i]) = v;
    }
}

// ---------------------------------------------------------------------------
// Flash attention v5: proven attn3 schedule (__syncthreads-staged), but
// 512-thread blocks: 8 waves share one 128-row q-supertile, so each 40KB
// K/V stage serves 2x the q-rows and 16 waves/CU hide LDS/latency.
// Grid 512 flat; tile = 15-(bid>>5) so longest (causal) blocks dispatch first.
// ---------------------------------------------------------------------------
__global__ __launch_bounds__(512, 4)
void attn5_kernel(const HT* __restrict__ qn, const HT* __restrict__ qr,
                  const HT* __restrict__ kn, const HT* __restrict__ kr16,
                  const HT* __restrict__ vt, HT* __restrict__ ao)
{
    __shared__ HT Ks_n[64 * 128];   // [krow][128] nope, src-swizzled
    __shared__ HT Ks_r[64 * 64];    // [krow][64] rope
    __shared__ HT Vs[128 * 64];     // [d][64 t]
    __shared__ HT Ps[8][16][72];

    const int tid  = threadIdx.x;
    const int lane = tid & 63;
    const int l15  = lane & 15, l4 = lane >> 4;
    const int w    = tid >> 6;                 // 0..7

    const int bid  = blockIdx.x;               // 512
    const int tile = 15 - (bid >> 5);          // descending: long blocks first
    const int h    = bid & 15;
    const int b    = (bid >> 4) & 1;

    const size_t bT = (size_t)b * Tn;
    const HT* vt_h = vt + ((size_t)(b * Hh + h) * 128) * Tn;

    const int qw = tile * 128 + 16 * w;

    // hoist Q fragments (192 dims = 6 frags of K=32)
    h8 aq[6];
    {
        const size_t rq = bT + qw + l15;
        const HT* pn = qn + rq * 2048 + h * 128 + l4 * 8;
        #pragma unroll
        for (int f = 0; f < 4; f++) aq[f] = *reinterpret_cast<const h8*>(pn + f * 32);
        const HT* pr = qr + rq * 1024 + h * 64 + l4 * 8;
        aq[4] = *reinterpret_cast<const h8*>(pr);
        aq[5] = *reinterpret_cast<const h8*>(pr + 32);
    }

    f32x4 o[8] = {};
    float m_i[4] = {-1e30f, -1e30f, -1e30f, -1e30f};
    float l_i[4] = {0.f, 0.f, 0.f, 0.f};

    const int nkb = (tile + 1) * 2;
    for (int kb64 = 0; kb64 < nkb; kb64++) {
        const int kb = kb64 * 64;
        __syncthreads();
        // ---- cooperative stage: 5 chunks per wave (40KB total) ----
        #pragma unroll
        for (int i = 0; i < 2; i++) {            // K nope 16KB (16 chunks)
            const int cc = w * 2 + i;
            const int r  = cc * 4 + l4;
            const int cl = (l15 & 8) | ((l15 & 7) ^ (r & 7));
            gload_lds16(kn + (bT + kb + r) * 2048 + h * 128 + cl * 8,
                        &Ks_n[cc * 512]);
        }
        {                                        // K rope 8KB (8 chunks)
            const int r  = w * 8 + (lane >> 3);
            const int cl = (lane & 7) ^ (r & 7);
            gload_lds16(kr16 + (bT + kb + r) * 64 + cl * 8,
                        &Ks_r[w * 512]);
        }
        #pragma unroll
        for (int i = 0; i < 2; i++) {            // V^T 16KB (16 chunks)
            const int cc = w * 2 + i;
            const int d  = cc * 8 + (lane >> 3);
            const int cl = (lane & 7) ^ (d & 7);
            gload_lds16(vt_h + (size_t)d * Tn + kb + cl * 8,
                        &Vs[cc * 512]);
        }
        __syncthreads();

        if (kb <= qw + 15) {
            // ---- QK^T ----
            f32x4 s[4] = {};
            #pragma unroll
            for (int c = 0; c < 4; c++) {
                const int kr = c * 16 + l15;
                const int sw = (kr & 7) << 4;
                const char* kbase = (const char*)Ks_n + kr * 256;
                #pragma unroll
                for (int f = 0; f < 4; f++)
                    s[c] = mfma16(aq[f], *(const h8*)(kbase + ((f * 64 + l4 * 16) ^ sw)), s[c]);
                const char* rbase = (const char*)Ks_r + kr * 128;
                s[c] = mfma16(aq[4], *(const h8*)(rbase + ((l4 * 16) ^ sw)), s[c]);
                s[c] = mfma16(aq[5], *(const h8*)(rbase + ((64 + l4 * 16) ^ sw)), s[c]);
            }
            // ---- online softmax ----
            const float scl = 0.07216878364870323f;  // 1/sqrt(192)
            float al[4];
            #pragma unroll
            for (int r = 0; r < 4; r++) {
                const int qrow = qw + l4 * 4 + r;
                float a[4];
                #pragma unroll
                for (int c = 0; c < 4; c++)
                    a[c] = (kb + c * 16 + l15 <= qrow) ? s[c][r] * scl : -1e30f;
                float mx = fmaxf(fmaxf(a[0], a[1]), fmaxf(a[2], a[3]));
                #pragma unroll
                for (int sh = 1; sh < 16; sh <<= 1) mx = fmaxf(mx, __shfl_xor(mx, sh));
                const float mn = fmaxf(m_i[r], mx);
                const float alpha = __expf(m_i[r] - mn);
                m_i[r] = mn;
                float rs = 0.f;
                #pragma unroll
                for (int c = 0; c < 4; c++) {
                    const float e = __expf(a[c] - mn);
                    rs += e;
                    Ps[w][l4 * 4 + r][c * 16 + l15] = (HT)e;
                }
                #pragma unroll
                for (int sh = 1; sh < 16; sh <<= 1) rs += __shfl_xor(rs, sh);
                l_i[r] = l_i[r] * alpha + rs;
                al[r] = alpha;
            }
            #pragma unroll
            for (int g = 0; g < 8; g++)
                #pragma unroll
                for (int r = 0; r < 4; r++) o[g][r] *= al[r];

            const h8 ap0 = *reinterpret_cast<const h8*>(&Ps[w][l15][l4 * 8]);
            const h8 ap1 = *reinterpret_cast<const h8*>(&Ps[w][l15][32 + l4 * 8]);

            // ---- O += P @ V ----
            #pragma unroll
            for (int g = 0; g < 8; g++) {
                const int d = g * 16 + l15;
                const int sw = (d & 7) << 4;
                const char* vbase = (const char*)Vs + d * 128;
                h8 v0 = *(const h8*)(vbase + ((l4 * 16) ^ sw));
                h8 v1 = *(const h8*)(vbase + ((64 + l4 * 16) ^ sw));
                o[g] = mfma16(ap0, v0, o[g]);
                o[g] = mfma16(ap1, v1, o[g]);
            }
        }
    }

    const size_t orow = bT + qw + l4 * 4;
    #pragma unroll
    for (int r = 0; r < 4; r++) {
        const float inv = 1.0f / l_i[r];
        HT* dst = ao + (orow + r) * 2048 + h * 128 + l15;
        #pragma unroll
        for (int g = 0; g < 8; g++) dst[g * 16] = (HT)(o[g][r] * inv);
    }
}

// ---------------------------------------------------------------------------
extern "C" void kernel_launch(void* const* d_in, const int* in_sizes, int n_in,
                              void* d_out, int out_size, void* d_ws, size_t ws_size,
                              hipStream_t stream)
{
    const float* x     = (const float*)d_in[0];
    const float* w_cq  = (const float*)d_in[1];
    const float* g_q   = (const float*)d_in[2];
    const float* w_ckv = (const float*)d_in[3];
    const float* g_kv  = (const float*)d_in[4];
    const float* w_dqn = (const float*)d_in[5];
    const float* w_dqr = (const float*)d_in[6];
    const float* w_dkn = (const float*)d_in[7];
    const float* w_dv  = (const float*)d_in[8];
    const float* w_kr  = (const float*)d_in[9];
    const float* w_out = (const float*)d_in[10];

    char* ws = (char*)d_ws;
    // weight region (dead after their GEMM -> vt aliases it)
    HT* cqT   = (HT*)(ws + 0);           // [1536][2048]  6,291,456
    HT* ckvT  = (HT*)(ws + 6291456);     // [512][2048]   2,097,152
    HT* krT   = (HT*)(ws + 8388608);     // [64][2048]      262,144
    //  pad region [8650752, 8912896) read as garbage B rows (never written out)
    HT* dqnT  = (HT*)(ws + 8912896);     // [2048][1536]  6,291,456
    HT* dqrT  = (HT*)(ws + 15204352);    // [1024][1536]  3,145,728
    HT* dknT  = (HT*)(ws + 18350080);    // [2048][512]   2,097,152
    HT* dvT   = (HT*)(ws + 20447232);    // [2048][512]   2,097,152
    HT* outT  = (HT*)(ws + 22544384);    // [2048][2048]  8,388,608
    HT* cq    = (HT*)(ws + 30932992);    // [4096][1536] 12,582,912
    HT* ckv   = (HT*)(ws + 43515904);    // [4096][512]   4,194,304
    HT* qn    = (HT*)(ws + 47710208);    // [4096][2048] 16,777,216 (x16/ao alias)
    HT* qr    = (HT*)(ws + 64487424);    // [4096][1024]  8,388,608
    HT* kn    = (HT*)(ws + 72876032);    // [4096][2048] 16,777,216
    HT* kr16  = (HT*)(ws + 89653248);    // [4096][64]      524,288  (end 90,177,536)
    HT* vt    = (HT*)(ws + 0);           // [2][16][128][2048] 16,777,216 (alias)
    HT* x16   = qn;                      // x16 dead before qn written
    HT* ao    = qn;                      // attn reads/writes same (row,h) slice

    float* out_o = (float*)d_out;
    float* out_k = out_o + (size_t)BT * Dm;
    float* out_v = out_k + (size_t)2 * Hh * Tn * 192;
    float2* cstab = (float2*)out_v;      // stashed in out_v head; KV GEMM
                                         // overwrites it AFTER last use (Q GEMM)

    const dim3 blk(256);

    cstab_kernel<<<dim3(256), blk, 0, stream>>>(cstab);
    // weight transposes: src [K][N] -> dst [N][K]
    wtrans_kernel<<<dim3(QRc/64,  Dm/64), blk, 0, stream>>>(w_cq,  cqT,  Dm,  QRc);
    wtrans_kernel<<<dim3(KVRc/64, Dm/64), blk, 0, stream>>>(w_ckv, ckvT, Dm,  KVRc);
    wtrans_kernel<<<dim3(RDc/64,  Dm/64), blk, 0, stream>>>(w_kr,  krT,  Dm,  RDc);
    wtrans_kernel<<<dim3(Dm/64, QRc/64),  blk, 0, stream>>>(w_dqn, dqnT, QRc, Dm);
    wtrans_kernel<<<dim3((Hh*RDc)/64, QRc/64), blk, 0, stream>>>(w_dqr, dqrT, QRc, Hh*RDc);
    wtrans_kernel<<<dim3(Dm/64, KVRc/64), blk, 0, stream>>>(w_dkn, dknT, KVRc, Dm);
    wtrans_kernel<<<dim3(Dm/64, KVRc/64), blk, 0, stream>>>(w_dv,  dvT,  KVRc, Dm);
    wtrans_kernel<<<dim3(Dm/64, Dm/64),   blk, 0, stream>>>(w_out, outT, Dm,  Dm);

    convx_kernel<<<dim3(4096), blk, 0, stream>>>(x, x16);

    // fused latent GEMM: N=2176 (cq | ckv | kr16-rope | pad)
    gemm16d<0><<<dim3(17, BT/128), blk, 0, stream>>>(x16, cqT, Dm,
        cq, ckv, kr16, nullptr, nullptr, cstab);
    kropebc_kernel<<<dim3(256), blk, 0, stream>>>(kr16, out_k);

    rmsnorm_kernel<<<dim3(BT), blk, 0, stream>>>(cq,  g_q,  QRc);
    rmsnorm_kernel<<<dim3(BT), blk, 0, stream>>>(ckv, g_kv, KVRc);

    // fused Q GEMM: N=3072 (qn | qr-rope)  [reads cstab; must precede KV GEMM]
    gemm16d<1><<<dim3(24, BT/128), blk, 0, stream>>>(cq, dqnT, QRc,
        qn, qr, nullptr, nullptr, nullptr, cstab);
    // fused KV GEMM: N=4096 (kn+out_k | vt+out_v)  [overwrites cstab & weight region]
    gemm16d<2><<<dim3(32, BT/128), blk, 0, stream>>>(ckv, dknT, KVRc,
        kn, nullptr, vt, out_k, out_v, nullptr);

    // attention (8-wave supertiles, longest-first dispatch)
    attn5_kernel<<<dim3(512), dim3(512), 0, stream>>>(qn, qr, kn, kr16, vt, ao);

    // output projection
    gemm16d<3><<<dim3(16, BT/128), blk, 0, stream>>>(ao, outT, Dm,
        nullptr, nullptr, nullptr, out_o, nullptr, nullptr);
}

// Round 6
// 382.692 us; speedup vs baseline: 3.5785x; 1.0062x over previous
//
#include <hip/hip_runtime.h>
#include <cstdint>
#include <cstddef>

typedef _Float16 HT;
typedef _Float16 h8 __attribute__((ext_vector_type(8)));
typedef _Float16 h4 __attribute__((ext_vector_type(4)));
typedef float f32x4 __attribute__((ext_vector_type(4)));

constexpr int Tn  = 2048;
constexpr int Dm  = 2048;
constexpr int Hh  = 16;
constexpr int RDc = 64;
constexpr int QRc = 1536;
constexpr int KVRc= 512;
constexpr int BT  = 4096;

#define VWAIT(N) asm volatile("s_waitcnt vmcnt(" #N ")" ::: "memory")
#define SBAR()   __builtin_amdgcn_s_barrier()

__device__ __forceinline__ f32x4 mfma16(h8 a, h8 b, f32x4 c) {
    return __builtin_amdgcn_mfma_f32_16x16x32_f16(a, b, c, 0, 0, 0);
}
__device__ __forceinline__ void gload_lds16(const void* g, void* l) {
    __builtin_amdgcn_global_load_lds(
        (const __attribute__((address_space(1))) unsigned int*)g,
        (__attribute__((address_space(3))) unsigned int*)l, 16, 0, 0);
}

// ---------------------------------------------------------------------------
// cos/sin table: cstab[t*32+i] = (cos, sin) of t * 10000^(-i/32)
// ---------------------------------------------------------------------------
__global__ __launch_bounds__(256)
void cstab_kernel(float2* __restrict__ cs)
{
    const int idx = blockIdx.x * 256 + threadIdx.x;   // 65536
    const int t = idx >> 5, i = idx & 31;
    const float ang = (float)t * exp2f(-(float)i * (13.287712379549449f / 32.f));
    cs[idx] = make_float2(cosf(ang), sinf(ang));
}

// ---------------------------------------------------------------------------
// Weight transpose+convert: src fp32 [K][N] -> dst fp16 [N][K]
// ---------------------------------------------------------------------------
__global__ __launch_bounds__(256)
void wtrans_kernel(const float* __restrict__ src, HT* __restrict__ dst,
                   int K, int N)
{
    __shared__ float Ts[64][65];
    const int k0 = blockIdx.y * 64, n0 = blockIdx.x * 64;
    const int tid = threadIdx.x;
    {
        const int r = tid >> 2, c0 = (tid & 3) * 16;
        const float* s = src + (size_t)(k0 + r) * N + n0 + c0;
        #pragma unroll
        for (int j = 0; j < 4; j++)
            *reinterpret_cast<f32x4*>(&Ts[r][c0 + j * 4]) = *reinterpret_cast<const f32x4*>(s + j * 4);
    }
    __syncthreads();
    {
        const int c = tid >> 2, kq = (tid & 3) * 16;
        h8 o0, o1;
        #pragma unroll
        for (int j = 0; j < 8; j++) { o0[j] = (HT)Ts[kq + j][c]; o1[j] = (HT)Ts[kq + 8 + j][c]; }
        HT* d = dst + (size_t)(n0 + c) * K + k0 + kq;
        *reinterpret_cast<h8*>(d)     = o0;
        *reinterpret_cast<h8*>(d + 8) = o1;
    }
}

// ---------------------------------------------------------------------------
__global__ __launch_bounds__(256)
void convx_kernel(const float* __restrict__ x, HT* __restrict__ x16)
{
    const size_t i = ((size_t)blockIdx.x * 256 + threadIdx.x) * 8;
    f32x4 a = *reinterpret_cast<const f32x4*>(x + i);
    f32x4 b = *reinterpret_cast<const f32x4*>(x + i + 4);
    h8 v;
    #pragma unroll
    for (int j = 0; j < 4; j++) { v[j] = (HT)a[j]; v[4 + j] = (HT)b[j]; }
    *reinterpret_cast<h8*>(x16 + i) = v;
}

// ---------------------------------------------------------------------------
// Double-buffered m97-style GEMM, 128x128 tile, BK=32, counted vmcnt.
// A fp16 [M][K], Bt fp16 [N][K]. EPI: 0=latent(cq|ckv|kr16-rope)
// 1=Q(qn|qr-rope) 2=KV(kn+out_k | vt+out_v) 3=OUT(fp32)
// ---------------------------------------------------------------------------
template<int EPI>
__global__ __launch_bounds__(256)
void gemm16d(const HT* __restrict__ A, const HT* __restrict__ Bt, const int K,
             HT* __restrict__ o1, HT* __restrict__ o2, HT* __restrict__ o3,
             float* __restrict__ f1, float* __restrict__ f2,
             const float2* __restrict__ cstab)
{
    __shared__ HT As[2][4096];
    __shared__ HT Bs[2][4096];

    const int tid  = threadIdx.x;
    const int lane = tid & 63;
    const int l15  = lane & 15, l4 = lane >> 4;
    const int w    = tid >> 6;
    const int wr   = w >> 1, wc = w & 1;
    const int m0   = blockIdx.y * 128;
    const int n0   = blockIdx.x * 128;

    f32x4 acc[4][4] = {};
    const int nk = K >> 5;

#define GSTAGE(as_, bs_, kt_) do {                                             \
    _Pragma("unroll")                                                          \
    for (int i_ = 0; i_ < 2; i_++) {                                           \
        const int row_ = (w * 2 + i_) * 16 + (lane >> 2);                      \
        gload_lds16(A  + (size_t)(m0 + row_) * K + (kt_) + (lane & 3) * 8,     \
                    (as_) + (w * 2 + i_) * 512);                               \
        gload_lds16(Bt + (size_t)(n0 + row_) * K + (kt_) + (lane & 3) * 8,     \
                    (bs_) + (w * 2 + i_) * 512);                               \
    } } while (0)

    GSTAGE(As[0], Bs[0], 0);

    for (int kt = 0; kt < nk; kt++) {
        HT* as = As[kt & 1];
        HT* bs = Bs[kt & 1];
        if (kt + 1 < nk) {
            GSTAGE(As[(kt + 1) & 1], Bs[(kt + 1) & 1], (kt + 1) * 32);
            VWAIT(4);
        } else {
            VWAIT(0);
        }
        SBAR();

        h8 af[4], bf[4];
        #pragma unroll
        for (int f = 0; f < 4; f++)
            af[f] = *reinterpret_cast<const h8*>(&as[(wr * 64 + f * 16 + l15) * 32 + l4 * 8]);
        #pragma unroll
        for (int g = 0; g < 4; g++)
            bf[g] = *reinterpret_cast<const h8*>(&bs[(wc * 64 + g * 16 + l15) * 32 + l4 * 8]);
        #pragma unroll
        for (int f = 0; f < 4; f++)
            #pragma unroll
            for (int g = 0; g < 4; g++)
                acc[f][g] = mfma16(af[f], bf[g], acc[f][g]);
        SBAR();
    }
#undef GSTAGE

    #pragma unroll
    for (int f = 0; f < 4; f++) {
        #pragma unroll
        for (int g = 0; g < 4; g++) {
            const int row = m0 + wr * 64 + f * 16 + l4 * 4;
            const int col = n0 + wc * 64 + g * 16 + l15;
            if constexpr (EPI == 3) {
                #pragma unroll
                for (int r = 0; r < 4; r++)
                    f1[(size_t)(row + r) * 2048 + col] = acc[f][g][r];
            } else if constexpr (EPI == 0) {
                if (col < 1536) {
                    #pragma unroll
                    for (int r = 0; r < 4; r++)
                        o1[(size_t)(row + r) * 1536 + col] = (HT)acc[f][g][r];
                } else if (col < 2048) {
                    #pragma unroll
                    for (int r = 0; r < 4; r++)
                        o2[(size_t)(row + r) * 512 + (col - 1536)] = (HT)acc[f][g][r];
                } else if (col < 2112) {
                    const int cc = col - 2048;
                    const int i = cc >> 1;
                    const bool odd = cc & 1;
                    #pragma unroll
                    for (int r = 0; r < 4; r++) {
                        const int t = (row + r) & (Tn - 1);
                        const float2 cs = cstab[t * 32 + i];
                        const float v = acc[f][g][r];
                        const float p = __shfl_xor(v, 1);
                        const float ov = odd ? p * cs.y + v * cs.x : v * cs.x - p * cs.y;
                        o3[(size_t)(row + r) * 64 + cc] = (HT)ov;
                    }
                }
            } else if constexpr (EPI == 1) {
                if (col < 2048) {
                    #pragma unroll
                    for (int r = 0; r < 4; r++)
                        o1[(size_t)(row + r) * 2048 + col] = (HT)acc[f][g][r];
                } else {
                    const int cc = col - 2048;
                    const int i = (cc & 63) >> 1;
                    const bool odd = cc & 1;
                    #pragma unroll
                    for (int r = 0; r < 4; r++) {
                        const int t = (row + r) & (Tn - 1);
                        const float2 cs = cstab[t * 32 + i];
                        const float v = acc[f][g][r];
                        const float p = __shfl_xor(v, 1);
                        const float ov = odd ? p * cs.y + v * cs.x : v * cs.x - p * cs.y;
                        o2[(size_t)(row + r) * 1024 + cc] = (HT)ov;
                    }
                }
            } else {  // EPI == 2
                if (col < 2048) {
                    const int h = col >> 7, d = col & 127;
                    #pragma unroll
                    for (int r = 0; r < 4; r++) {
                        const int rw = row + r;
                        const int b = rw >> 11, t = rw & (Tn - 1);
                        o1[(size_t)rw * 2048 + col] = (HT)acc[f][g][r];
                        f1[((size_t)(b * Hh + h) * Tn + t) * 192 + d] = acc[f][g][r];
                    }
                } else {
                    const int c2 = col - 2048;
                    const int h = c2 >> 7, d = c2 & 127;
                    const int b = row >> 11, t0 = row & (Tn - 1);
                    h4 pk;
                    #pragma unroll
                    for (int r = 0; r < 4; r++) {
                        f2[((size_t)(b * Hh + h) * Tn + t0 + r) * 128 + d] = acc[f][g][r];
                        pk[r] = (HT)acc[f][g][r];
                    }
                    *reinterpret_cast<h4*>(&o3[((size_t)(b * Hh + h) * 128 + d) * Tn + t0]) = pk;
                }
            }
        }
    }
}

// ---------------------------------------------------------------------------
// broadcast rope slice of out_k across 16 heads (fp32)
// ---------------------------------------------------------------------------
__global__ __launch_bounds__(256)
void kropebc_kernel(const HT* __restrict__ kr16, float* __restrict__ out_k)
{
    const int idx = blockIdx.x * 256 + threadIdx.x;    // 2*2048*16
    const int j4 = (idx & 15) * 4;
    const int t  = (idx >> 4) & (Tn - 1);
    const int b  = idx >> 15;
    h4 v = *reinterpret_cast<const h4*>(&kr16[((size_t)(b * Tn + t)) * 64 + j4]);
    f32x4 f;
    #pragma unroll
    for (int r = 0; r < 4; r++) f[r] = (float)v[r];
    #pragma unroll
    for (int h = 0; h < Hh; h++)
        *reinterpret_cast<f32x4*>(&out_k[((size_t)(b * Hh + h) * Tn + t) * 192 + 128 + j4]) = f;
}

// ---------------------------------------------------------------------------
__global__ __launch_bounds__(256)
void rmsnorm_kernel(HT* __restrict__ X, const float* __restrict__ g, int N)
{
    const int row = blockIdx.x;
    HT* x = X + (size_t)row * N;
    float ss = 0.f;
    for (int i = threadIdx.x * 8; i < N; i += 2048) {
        h8 v = *reinterpret_cast<const h8*>(&x[i]);
        #pragma unroll
        for (int j = 0; j < 8; j++) { float f = (float)v[j]; ss += f * f; }
    }
    #pragma unroll
    for (int sh = 32; sh >= 1; sh >>= 1) ss += __shfl_xor(ss, sh);
    __shared__ float red[4];
    if ((threadIdx.x & 63) == 0) red[threadIdx.x >> 6] = ss;
    __syncthreads();
    const float tot = red[0] + red[1] + red[2] + red[3];
    const float scale = rsqrtf(tot / (float)N + 1e-6f);
    for (int i = threadIdx.x * 8; i < N; i += 2048) {
        h8 v = *reinterpret_cast<const h8*>(&x[i]);
        f32x4 g0 = *reinterpret_cast<const f32x4*>(&g[i]);
        f32x4 g1 = *reinterpret_cast<const f32x4*>(&g[i + 4]);
        #pragma unroll
        for (int j = 0; j < 4; j++) { v[j]   = (HT)((float)v[j]   * scale * g0[j]);
                                      v[4+j] = (HT)((float)v[4+j] * scale * g1[j]); }
        *reinterpret_cast<h8*>(&x[i]) = v;
    }
}

// ---------------------------------------------------------------------------
// Flash attention v6: attn3 compute schedule, rebalanced.
// Grid 1024 x 256thr: bid -> tile 31-(bid>>5) (descending work, 64 q-rows),
// (h,b) = bid&31. nkb = tile+1 varies 32..1 -> 1024 jobs on 768 resident
// slots (LDS 41KB -> 3 blocks/CU) gives dynamic backfill balance.
// K-rope read directly from L2-resident kr16 (no LDS staging).
// ---------------------------------------------------------------------------
__global__ __launch_bounds__(256)
void attn6_kernel(const HT* __restrict__ qn, const HT* __restrict__ qr,
                  const HT* __restrict__ kn, const HT* __restrict__ kr16,
                  const HT* __restrict__ vt, HT* __restrict__ ao)
{
    __shared__ HT Ks_n[64 * 128];   // [krow][128] nope, src-swizzled
    __shared__ HT Vs[128 * 64];     // [d][64 t]
    __shared__ HT Ps[4][16][72];

    const int tid  = threadIdx.x;
    const int lane = tid & 63;
    const int l15  = lane & 15, l4 = lane >> 4;
    const int w    = tid >> 6;

    const int bid  = blockIdx.x;               // 1024
    const int tile = 31 - (bid >> 5);          // descending: long jobs first
    const int h    = bid & 15;
    const int b    = (bid >> 4) & 1;

    const size_t bT = (size_t)b * Tn;
    const HT* vt_h = vt + ((size_t)(b * Hh + h) * 128) * Tn;
    const HT* krb  = kr16 + bT * 64;

    const int qw = tile * 64 + 16 * w;

    // hoist Q fragments (192 dims = 6 frags of K=32)
    h8 aq[6];
    {
        const size_t rq = bT + qw + l15;
        const HT* pn = qn + rq * 2048 + h * 128 + l4 * 8;
        #pragma unroll
        for (int f = 0; f < 4; f++) aq[f] = *reinterpret_cast<const h8*>(pn + f * 32);
        const HT* pr = qr + rq * 1024 + h * 64 + l4 * 8;
        aq[4] = *reinterpret_cast<const h8*>(pr);
        aq[5] = *reinterpret_cast<const h8*>(pr + 32);
    }

    f32x4 o[8] = {};
    float m_i[4] = {-1e30f, -1e30f, -1e30f, -1e30f};
    float l_i[4] = {0.f, 0.f, 0.f, 0.f};

    const int nkb = tile + 1;
    for (int kb64 = 0; kb64 < nkb; kb64++) {
        const int kb = kb64 * 64;
        __syncthreads();
        // ---- cooperative stage: K-nope + V^T (8 chunks per wave) ----
        #pragma unroll
        for (int j = 0; j < 4; j++) {            // K nope 16KB (16 chunks)
            const int r = (w * 4 + j) * 4 + l4;
            const int cl = (l15 & 8) | ((l15 & 7) ^ (r & 7));
            gload_lds16(kn + (bT + kb + r) * 2048 + h * 128 + cl * 8,
                        &Ks_n[(w * 4 + j) * 512]);
        }
        #pragma unroll
        for (int j = 0; j < 4; j++) {            // V^T 16KB (16 chunks)
            const int d = (w * 4 + j) * 8 + (lane >> 3);
            const int cl = (lane & 7) ^ (d & 7);
            gload_lds16(vt_h + (size_t)d * Tn + kb + cl * 8,
                        &Vs[(w * 4 + j) * 512]);
        }
        __syncthreads();

        if (kb <= qw + 15) {
            // ---- QK^T (rope b-frags straight from L2) ----
            f32x4 s[4] = {};
            __builtin_amdgcn_s_setprio(1);
            #pragma unroll
            for (int c = 0; c < 4; c++) {
                const int kr = c * 16 + l15;
                const HT* rp = krb + (size_t)(kb + kr) * 64 + l4 * 8;
                const h8 br0 = *reinterpret_cast<const h8*>(rp);
                const h8 br1 = *reinterpret_cast<const h8*>(rp + 32);
                const int sw = (kr & 7) << 4;
                const char* kbase = (const char*)Ks_n + kr * 256;
                #pragma unroll
                for (int f = 0; f < 4; f++)
                    s[c] = mfma16(aq[f], *(const h8*)(kbase + ((f * 64 + l4 * 16) ^ sw)), s[c]);
                s[c] = mfma16(aq[4], br0, s[c]);
                s[c] = mfma16(aq[5], br1, s[c]);
            }
            __builtin_amdgcn_s_setprio(0);
            // ---- online softmax ----
            const float scl = 0.07216878364870323f;  // 1/sqrt(192)
            float al[4];
            #pragma unroll
            for (int r = 0; r < 4; r++) {
                const int qrow = qw + l4 * 4 + r;
                float a[4];
                #pragma unroll
                for (int c = 0; c < 4; c++)
                    a[c] = (kb + c * 16 + l15 <= qrow) ? s[c][r] * scl : -1e30f;
                float mx = fmaxf(fmaxf(a[0], a[1]), fmaxf(a[2], a[3]));
                #pragma unroll
                for (int sh = 1; sh < 16; sh <<= 1) mx = fmaxf(mx, __shfl_xor(mx, sh));
                const float mn = fmaxf(m_i[r], mx);
                const float alpha = __expf(m_i[r] - mn);
                m_i[r] = mn;
                float rs = 0.f;
                #pragma unroll
                for (int c = 0; c < 4; c++) {
                    const float e = __expf(a[c] - mn);
                    rs += e;
                    Ps[w][l4 * 4 + r][c * 16 + l15] = (HT)e;
                }
                #pragma unroll
                for (int sh = 1; sh < 16; sh <<= 1) rs += __shfl_xor(rs, sh);
                l_i[r] = l_i[r] * alpha + rs;
                al[r] = alpha;
            }
            #pragma unroll
            for (int g = 0; g < 8; g++)
                #pragma unroll
                for (int r = 0; r < 4; r++) o[g][r] *= al[r];

            const h8 ap0 = *reinterpret_cast<const h8*>(&Ps[w][l15][l4 * 8]);
            const h8 ap1 = *reinterpret_cast<const h8*>(&Ps[w][l15][32 + l4 * 8]);

            // ---- O += P @ V ----
            __builtin_amdgcn_s_setprio(1);
            #pragma unroll
            for (int g = 0; g < 8; g++) {
                const int d = g * 16 + l15;
                const int sw = (d & 7) << 4;
                const char* vbase = (const char*)Vs + d * 128;
                h8 v0 = *(const h8*)(vbase + ((l4 * 16) ^ sw));
                h8 v1 = *(const h8*)(vbase + ((64 + l4 * 16) ^ sw));
                o[g] = mfma16(ap0, v0, o[g]);
                o[g] = mfma16(ap1, v1, o[g]);
            }
            __builtin_amdgcn_s_setprio(0);
        }
    }

    const size_t orow = bT + qw + l4 * 4;
    #pragma unroll
    for (int r = 0; r < 4; r++) {
        const float inv = 1.0f / l_i[r];
        HT* dst = ao + (orow + r) * 2048 + h * 128 + l15;
        #pragma unroll
        for (int g = 0; g < 8; g++) dst[g * 16] = (HT)(o[g][r] * inv);
    }
}

// ---------------------------------------------------------------------------
extern "C" void kernel_launch(void* const* d_in, const int* in_sizes, int n_in,
                              void* d_out, int out_size, void* d_ws, size_t ws_size,
                              hipStream_t stream)
{
    const float* x     = (const float*)d_in[0];
    const float* w_cq  = (const float*)d_in[1];
    const float* g_q   = (const float*)d_in[2];
    const float* w_ckv = (const float*)d_in[3];
    const float* g_kv  = (const float*)d_in[4];
    const float* w_dqn = (const float*)d_in[5];
    const float* w_dqr = (const float*)d_in[6];
    const float* w_dkn = (const float*)d_in[7];
    const float* w_dv  = (const float*)d_in[8];
    const float* w_kr  = (const float*)d_in[9];
    const float* w_out = (const float*)d_in[10];

    char* ws = (char*)d_ws;
    // weight region (dead after their GEMM -> vt aliases it)
    HT* cqT   = (HT*)(ws + 0);           // [1536][2048]  6,291,456
    HT* ckvT  = (HT*)(ws + 6291456);     // [512][2048]   2,097,152
    HT* krT   = (HT*)(ws + 8388608);     // [64][2048]      262,144
    //  pad region [8650752, 8912896) read as garbage B rows (never written out)
    HT* dqnT  = (HT*)(ws + 8912896);     // [2048][1536]  6,291,456
    HT* dqrT  = (HT*)(ws + 15204352);    // [1024][1536]  3,145,728
    HT* dknT  = (HT*)(ws + 18350080);    // [2048][512]   2,097,152
    HT* dvT   = (HT*)(ws + 20447232);    // [2048][512]   2,097,152
    HT* outT  = (HT*)(ws + 22544384);    // [2048][2048]  8,388,608
    HT* cq    = (HT*)(ws + 30932992);    // [4096][1536] 12,582,912
    HT* ckv   = (HT*)(ws + 43515904);    // [4096][512]   4,194,304
    HT* qn    = (HT*)(ws + 47710208);    // [4096][2048] 16,777,216 (x16/ao alias)
    HT* qr    = (HT*)(ws + 64487424);    // [4096][1024]  8,388,608
    HT* kn    = (HT*)(ws + 72876032);    // [4096][2048] 16,777,216
    HT* kr16  = (HT*)(ws + 89653248);    // [4096][64]      524,288  (end 90,177,536)
    HT* vt    = (HT*)(ws + 0);           // [2][16][128][2048] 16,777,216 (alias)
    HT* x16   = qn;                      // x16 dead before qn written
    HT* ao    = qn;                      // attn reads/writes same (row,h) slice

    float* out_o = (float*)d_out;
    float* out_k = out_o + (size_t)BT * Dm;
    float* out_v = out_k + (size_t)2 * Hh * Tn * 192;
    float2* cstab = (float2*)out_v;      // stashed in out_v head; KV GEMM
                                         // overwrites it AFTER last use (Q GEMM)

    const dim3 blk(256);

    cstab_kernel<<<dim3(256), blk, 0, stream>>>(cstab);
    // weight transposes: src [K][N] -> dst [N][K]
    wtrans_kernel<<<dim3(QRc/64,  Dm/64), blk, 0, stream>>>(w_cq,  cqT,  Dm,  QRc);
    wtrans_kernel<<<dim3(KVRc/64, Dm/64), blk, 0, stream>>>(w_ckv, ckvT, Dm,  KVRc);
    wtrans_kernel<<<dim3(RDc/64,  Dm/64), blk, 0, stream>>>(w_kr,  krT,  Dm,  RDc);
    wtrans_kernel<<<dim3(Dm/64, QRc/64),  blk, 0, stream>>>(w_dqn, dqnT, QRc, Dm);
    wtrans_kernel<<<dim3((Hh*RDc)/64, QRc/64), blk, 0, stream>>>(w_dqr, dqrT, QRc, Hh*RDc);
    wtrans_kernel<<<dim3(Dm/64, KVRc/64), blk, 0, stream>>>(w_dkn, dknT, KVRc, Dm);
    wtrans_kernel<<<dim3(Dm/64, KVRc/64), blk, 0, stream>>>(w_dv,  dvT,  KVRc, Dm);
    wtrans_kernel<<<dim3(Dm/64, Dm/64),   blk, 0, stream>>>(w_out, outT, Dm,  Dm);

    convx_kernel<<<dim3(4096), blk, 0, stream>>>(x, x16);

    // fused latent GEMM: N=2176 (cq | ckv | kr16-rope | pad)
    gemm16d<0><<<dim3(17, BT/128), blk, 0, stream>>>(x16, cqT, Dm,
        cq, ckv, kr16, nullptr, nullptr, cstab);
    kropebc_kernel<<<dim3(256), blk, 0, stream>>>(kr16, out_k);

    rmsnorm_kernel<<<dim3(BT), blk, 0, stream>>>(cq,  g_q,  QRc);
    rmsnorm_kernel<<<dim3(BT), blk, 0, stream>>>(ckv, g_kv, KVRc);

    // fused Q GEMM: N=3072 (qn | qr-rope)  [reads cstab; must precede KV GEMM]
    gemm16d<1><<<dim3(24, BT/128), blk, 0, stream>>>(cq, dqnT, QRc,
        qn, qr, nullptr, nullptr, nullptr, cstab);
    // fused KV GEMM: N=4096 (kn+out_k | vt+out_v)  [overwrites cstab & weight region]
    gemm16d<2><<<dim3(32, BT/128), blk, 0, stream>>>(ckv, dknT, KVRc,
        kn, nullptr, vt, out_k, out_v, nullptr);

    // attention (1024 descending jobs, 3 blocks/CU backfill balance)
    attn6_kernel<<<dim3(1024), blk, 0, stream>>>(qn, qr, kn, kr16, vt, ao);

    // output projection
    gemm16d<3><<<dim3(16, BT/128), blk, 0, stream>>>(ao, outT, Dm,
        nullptr, nullptr, nullptr, out_o, nullptr, nullptr);
}

// Round 7
// 357.788 us; speedup vs baseline: 3.8276x; 1.0696x over previous
//
#include <hip/hip_runtime.h>
#include <cstdint>
#include <cstddef>

typedef _Float16 HT;
typedef _Float16 h8 __attribute__((ext_vector_type(8)));
typedef _Float16 h4 __attribute__((ext_vector_type(4)));
typedef float f32x4 __attribute__((ext_vector_type(4)));

constexpr int Tn  = 2048;
constexpr int Dm  = 2048;
constexpr int Hh  = 16;
constexpr int RDc = 64;
constexpr int QRc = 1536;
constexpr int KVRc= 512;
constexpr int BT  = 4096;

#define VWAIT(N) asm volatile("s_waitcnt vmcnt(" #N ")" ::: "memory")
#define SBAR()   __builtin_amdgcn_s_barrier()

__device__ __forceinline__ f32x4 mfma16(h8 a, h8 b, f32x4 c) {
    return __builtin_amdgcn_mfma_f32_16x16x32_f16(a, b, c, 0, 0, 0);
}
__device__ __forceinline__ void gload_lds16(const void* g, void* l) {
    __builtin_amdgcn_global_load_lds(
        (const __attribute__((address_space(1))) unsigned int*)g,
        (__attribute__((address_space(3))) unsigned int*)l, 16, 0, 0);
}

// ---------------------------------------------------------------------------
// cos/sin table: cstab[t*32+i] = (cos, sin) of t * 10000^(-i/32)
// ---------------------------------------------------------------------------
__global__ __launch_bounds__(256)
void cstab_kernel(float2* __restrict__ cs)
{
    const int idx = blockIdx.x * 256 + threadIdx.x;   // 65536
    const int t = idx >> 5, i = idx & 31;
    const float ang = (float)t * exp2f(-(float)i * (13.287712379549449f / 32.f));
    cs[idx] = make_float2(cosf(ang), sinf(ang));
}

// ---------------------------------------------------------------------------
// Merged weight transpose+convert: 8 segments, src fp32 [K][N] -> dst [N][K]
// ---------------------------------------------------------------------------
struct WT8 {
    const float* s[8];
    HT* d[8];
    int K[8], N[8], start[8];
};

__global__ __launch_bounds__(256)
void wtrans8_kernel(WT8 p)
{
    __shared__ float Ts[64][65];
    int seg = 0;
    #pragma unroll
    for (int i = 1; i < 8; i++) if ((int)blockIdx.x >= p.start[i]) seg = i;
    const float* src = p.s[seg];
    HT* dst = p.d[seg];
    const int K = p.K[seg], N = p.N[seg];
    const int bx = blockIdx.x - p.start[seg];
    const int nx = N >> 6;
    const int n0 = (bx % nx) * 64, k0 = (bx / nx) * 64;
    const int tid = threadIdx.x;
    {
        const int r = tid >> 2, c0 = (tid & 3) * 16;
        const float* s = src + (size_t)(k0 + r) * N + n0 + c0;
        #pragma unroll
        for (int j = 0; j < 4; j++)
            *reinterpret_cast<f32x4*>(&Ts[r][c0 + j * 4]) = *reinterpret_cast<const f32x4*>(s + j * 4);
    }
    __syncthreads();
    {
        const int c = tid >> 2, kq = (tid & 3) * 16;
        h8 o0, o1;
        #pragma unroll
        for (int j = 0; j < 8; j++) { o0[j] = (HT)Ts[kq + j][c]; o1[j] = (HT)Ts[kq + 8 + j][c]; }
        HT* d = dst + (size_t)(n0 + c) * K + k0 + kq;
        *reinterpret_cast<h8*>(d)     = o0;
        *reinterpret_cast<h8*>(d + 8) = o1;
    }
}

// ---------------------------------------------------------------------------
__global__ __launch_bounds__(256)
void convx_kernel(const float* __restrict__ x, HT* __restrict__ x16)
{
    const size_t i = ((size_t)blockIdx.x * 256 + threadIdx.x) * 8;
    f32x4 a = *reinterpret_cast<const f32x4*>(x + i);
    f32x4 b = *reinterpret_cast<const f32x4*>(x + i + 4);
    h8 v;
    #pragma unroll
    for (int j = 0; j < 4; j++) { v[j] = (HT)a[j]; v[4 + j] = (HT)b[j]; }
    *reinterpret_cast<h8*>(x16 + i) = v;
}

// ---------------------------------------------------------------------------
// Double-buffered m97-style GEMM, 128x128 tile, BK=32, counted vmcnt.
// LDS 2-bit XOR swizzle (slot = l4 ^ (row&3) ^ ((row>>2)&3)) applied on BOTH
// the glds source index and the ds_read index -> 8-way conflict becomes 2-way.
// A fp16 [M][K], Bt fp16 [N][K]. EPI: 0=latent(cq|ckv|kr16-rope)
// 1=Q(qn|qr-rope) 2=KV(kn+out_k | vt+out_v) 3=OUT(fp32)
// ---------------------------------------------------------------------------
template<int EPI>
__global__ __launch_bounds__(256)
void gemm16d(const HT* __restrict__ A, const HT* __restrict__ Bt, const int K,
             HT* __restrict__ o1, HT* __restrict__ o2, HT* __restrict__ o3,
             float* __restrict__ f1, float* __restrict__ f2,
             const float2* __restrict__ cstab)
{
    __shared__ HT As[2][4096];
    __shared__ HT Bs[2][4096];

    const int tid  = threadIdx.x;
    const int lane = tid & 63;
    const int l15  = lane & 15, l4 = lane >> 4;
    const int w    = tid >> 6;
    const int wr   = w >> 1, wc = w & 1;
    const int m0   = blockIdx.y * 128;
    const int n0   = blockIdx.x * 128;

    f32x4 acc[4][4] = {};
    const int nk = K >> 5;

    // stage source k-chunk pre-swizzle (inverse of read swizzle; involution)
    const int schunk = ((lane & 3) ^ ((lane >> 2) & 3) ^ ((lane >> 4) & 3)) * 8;

#define GSTAGE(as_, bs_, kt_) do {                                             \
    _Pragma("unroll")                                                          \
    for (int i_ = 0; i_ < 2; i_++) {                                           \
        const int row_ = (w * 2 + i_) * 16 + (lane >> 2);                      \
        gload_lds16(A  + (size_t)(m0 + row_) * K + (kt_) + schunk,             \
                    (as_) + (w * 2 + i_) * 512);                               \
        gload_lds16(Bt + (size_t)(n0 + row_) * K + (kt_) + schunk,             \
                    (bs_) + (w * 2 + i_) * 512);                               \
    } } while (0)

    GSTAGE(As[0], Bs[0], 0);

    // read-side swizzled k-slot (constant per thread)
    const int sl = (l4 ^ (l15 & 3) ^ ((l15 >> 2) & 3)) * 8;

    for (int kt = 0; kt < nk; kt++) {
        HT* as = As[kt & 1];
        HT* bs = Bs[kt & 1];
        if (kt + 1 < nk) {
            GSTAGE(As[(kt + 1) & 1], Bs[(kt + 1) & 1], (kt + 1) * 32);
            VWAIT(4);
        } else {
            VWAIT(0);
        }
        SBAR();

        h8 af[4], bf[4];
        #pragma unroll
        for (int f = 0; f < 4; f++)
            af[f] = *reinterpret_cast<const h8*>(&as[(wr * 64 + f * 16 + l15) * 32 + sl]);
        #pragma unroll
        for (int g = 0; g < 4; g++)
            bf[g] = *reinterpret_cast<const h8*>(&bs[(wc * 64 + g * 16 + l15) * 32 + sl]);
        #pragma unroll
        for (int f = 0; f < 4; f++)
            #pragma unroll
            for (int g = 0; g < 4; g++)
                acc[f][g] = mfma16(af[f], bf[g], acc[f][g]);
        SBAR();
    }
#undef GSTAGE

    #pragma unroll
    for (int f = 0; f < 4; f++) {
        #pragma unroll
        for (int g = 0; g < 4; g++) {
            const int row = m0 + wr * 64 + f * 16 + l4 * 4;
            const int col = n0 + wc * 64 + g * 16 + l15;
            if constexpr (EPI == 3) {
                #pragma unroll
                for (int r = 0; r < 4; r++)
                    f1[(size_t)(row + r) * 2048 + col] = acc[f][g][r];
            } else if constexpr (EPI == 0) {
                if (col < 1536) {
                    #pragma unroll
                    for (int r = 0; r < 4; r++)
                        o1[(size_t)(row + r) * 1536 + col] = (HT)acc[f][g][r];
                } else if (col < 2048) {
                    #pragma unroll
                    for (int r = 0; r < 4; r++)
                        o2[(size_t)(row + r) * 512 + (col - 1536)] = (HT)acc[f][g][r];
                } else if (col < 2112) {
                    const int cc = col - 2048;
                    const int i = cc >> 1;
                    const bool odd = cc & 1;
                    #pragma unroll
                    for (int r = 0; r < 4; r++) {
                        const int t = (row + r) & (Tn - 1);
                        const float2 cs = cstab[t * 32 + i];
                        const float v = acc[f][g][r];
                        const float p = __shfl_xor(v, 1);
                        const float ov = odd ? p * cs.y + v * cs.x : v * cs.x - p * cs.y;
                        o3[(size_t)(row + r) * 64 + cc] = (HT)ov;
                    }
                }
            } else if constexpr (EPI == 1) {
                if (col < 2048) {
                    #pragma unroll
                    for (int r = 0; r < 4; r++)
                        o1[(size_t)(row + r) * 2048 + col] = (HT)acc[f][g][r];
                } else {
                    const int cc = col - 2048;
                    const int i = (cc & 63) >> 1;
                    const bool odd = cc & 1;
                    #pragma unroll
                    for (int r = 0; r < 4; r++) {
                        const int t = (row + r) & (Tn - 1);
                        const float2 cs = cstab[t * 32 + i];
                        const float v = acc[f][g][r];
                        const float p = __shfl_xor(v, 1);
                        const float ov = odd ? p * cs.y + v * cs.x : v * cs.x - p * cs.y;
                        o2[(size_t)(row + r) * 1024 + cc] = (HT)ov;
                    }
                }
            } else {  // EPI == 2
                if (col < 2048) {
                    const int h = col >> 7, d = col & 127;
                    #pragma unroll
                    for (int r = 0; r < 4; r++) {
                        const int rw = row + r;
                        const int b = rw >> 11, t = rw & (Tn - 1);
                        o1[(size_t)rw * 2048 + col] = (HT)acc[f][g][r];
                        f1[((size_t)(b * Hh + h) * Tn + t) * 192 + d] = acc[f][g][r];
                    }
                } else {
                    const int c2 = col - 2048;
                    const int h = c2 >> 7, d = c2 & 127;
                    const int b = row >> 11, t0 = row & (Tn - 1);
                    h4 pk;
                    #pragma unroll
                    for (int r = 0; r < 4; r++) {
                        f2[((size_t)(b * Hh + h) * Tn + t0 + r) * 128 + d] = acc[f][g][r];
                        pk[r] = (HT)acc[f][g][r];
                    }
                    *reinterpret_cast<h4*>(&o3[((size_t)(b * Hh + h) * 128 + d) * Tn + t0]) = pk;
                }
            }
        }
    }
}

// ---------------------------------------------------------------------------
// broadcast rope slice of out_k across 16 heads (fp32)
// ---------------------------------------------------------------------------
__global__ __launch_bounds__(256)
void kropebc_kernel(const HT* __restrict__ kr16, float* __restrict__ out_k)
{
    const int idx = blockIdx.x * 256 + threadIdx.x;    // 2*2048*16
    const int j4 = (idx & 15) * 4;
    const int t  = (idx >> 4) & (Tn - 1);
    const int b  = idx >> 15;
    h4 v = *reinterpret_cast<const h4*>(&kr16[((size_t)(b * Tn + t)) * 64 + j4]);
    f32x4 f;
    #pragma unroll
    for (int r = 0; r < 4; r++) f[r] = (float)v[r];
    #pragma unroll
    for (int h = 0; h < Hh; h++)
        *reinterpret_cast<f32x4*>(&out_k[((size_t)(b * Hh + h) * Tn + t) * 192 + 128 + j4]) = f;
}

// ---------------------------------------------------------------------------
// merged RMSNorm: grid (4096, 2); y=0 -> (Xa, ga, 1536), y=1 -> (Xb, gb, 512)
// ---------------------------------------------------------------------------
__global__ __launch_bounds__(256)
void rmsnorm2_kernel(HT* __restrict__ Xa, const float* __restrict__ ga,
                     HT* __restrict__ Xb, const float* __restrict__ gb)
{
    const int which = blockIdx.y;
    HT* X = which ? Xb : Xa;
    const float* g = which ? gb : ga;
    const int N = which ? 512 : 1536;
    const int row = blockIdx.x;
    HT* x = X + (size_t)row * N;
    float ss = 0.f;
    for (int i = threadIdx.x * 8; i < N; i += 2048) {
        h8 v = *reinterpret_cast<const h8*>(&x[i]);
        #pragma unroll
        for (int j = 0; j < 8; j++) { float f = (float)v[j]; ss += f * f; }
    }
    #pragma unroll
    for (int sh = 32; sh >= 1; sh >>= 1) ss += __shfl_xor(ss, sh);
    __shared__ float red[4];
    if ((threadIdx.x & 63) == 0) red[threadIdx.x >> 6] = ss;
    __syncthreads();
    const float tot = red[0] + red[1] + red[2] + red[3];
    const float scale = rsqrtf(tot / (float)N + 1e-6f);
    for (int i = threadIdx.x * 8; i < N; i += 2048) {
        h8 v = *reinterpret_cast<const h8*>(&x[i]);
        f32x4 g0 = *reinterpret_cast<const f32x4*>(&g[i]);
        f32x4 g1 = *reinterpret_cast<const f32x4*>(&g[i + 4]);
        #pragma unroll
        for (int j = 0; j < 4; j++) { v[j]   = (HT)((float)v[j]   * scale * g0[j]);
                                      v[4+j] = (HT)((float)v[4+j] * scale * g1[j]); }
        *reinterpret_cast<h8*>(&x[i]) = v;
    }
}

// ---------------------------------------------------------------------------
// Flash attention v7: QBLK=32 per wave via mirrored q-tiles.
// Wave w of block (j,h,b) owns qf0 = rows of 64-tile j (low, causal-short)
// and qf1 = rows of 64-tile 31-j (high, active every iteration).
// Per-wave compute = (j+1)+(32-j) = 33 k-blocks -> uniform across all blocks.
// K/V fragment LDS reads and 32KB staging now amortize over 2x q-rows.
// ---------------------------------------------------------------------------
__global__ __launch_bounds__(256, 2)
void attn7_kernel(const HT* __restrict__ qn, const HT* __restrict__ qr,
                  const HT* __restrict__ kn, const HT* __restrict__ kr16,
                  const HT* __restrict__ vt, HT* __restrict__ ao)
{
    __shared__ HT Ks_n[64 * 128];   // [krow][128] nope, src-swizzled
    __shared__ HT Vs[128 * 64];     // [d][64 t]
    __shared__ HT Ps[4][32][72];    // per-wave P rows: 0-15 qf0, 16-31 qf1

    const int tid  = threadIdx.x;
    const int lane = tid & 63;
    const int l15  = lane & 15, l4 = lane >> 4;
    const int w    = tid >> 6;

    const int bid = blockIdx.x;          // 512
    const int j   = bid >> 5;            // 0..15
    const int h   = bid & 15;
    const int b   = (bid >> 4) & 1;
    const int thi = 31 - j;

    const size_t bT = (size_t)b * Tn;
    const HT* vt_h = vt + ((size_t)(b * Hh + h) * 128) * Tn;
    const HT* krb  = kr16 + bT * 64;

    const int qw0 = j   * 64 + w * 16;
    const int qw1 = thi * 64 + w * 16;

    // hoist both Q fragment sets
    h8 aq0[6], aq1[6];
    {
        const size_t rq0 = bT + qw0 + l15;
        const HT* pn = qn + rq0 * 2048 + h * 128 + l4 * 8;
        #pragma unroll
        for (int f = 0; f < 4; f++) aq0[f] = *reinterpret_cast<const h8*>(pn + f * 32);
        const HT* pr = qr + rq0 * 1024 + h * 64 + l4 * 8;
        aq0[4] = *reinterpret_cast<const h8*>(pr);
        aq0[5] = *reinterpret_cast<const h8*>(pr + 32);
        const size_t rq1 = bT + qw1 + l15;
        const HT* pn1 = qn + rq1 * 2048 + h * 128 + l4 * 8;
        #pragma unroll
        for (int f = 0; f < 4; f++) aq1[f] = *reinterpret_cast<const h8*>(pn1 + f * 32);
        const HT* pr1 = qr + rq1 * 1024 + h * 64 + l4 * 8;
        aq1[4] = *reinterpret_cast<const h8*>(pr1);
        aq1[5] = *reinterpret_cast<const h8*>(pr1 + 32);
    }

    f32x4 o0[8] = {}, o1[8] = {};
    float m0v[4] = {-1e30f, -1e30f, -1e30f, -1e30f};
    float m1v[4] = {-1e30f, -1e30f, -1e30f, -1e30f};
    float l0v[4] = {0.f, 0.f, 0.f, 0.f};
    float l1v[4] = {0.f, 0.f, 0.f, 0.f};

    const float scl = 0.07216878364870323f;  // 1/sqrt(192)

#define SOFTMAX(sv, mv, lv, ov, qwx, prow)                                      \
{                                                                               \
    float al_[4];                                                               \
    _Pragma("unroll")                                                           \
    for (int r = 0; r < 4; r++) {                                               \
        const int qrow = (qwx) + l4 * 4 + r;                                    \
        float a_[4];                                                            \
        _Pragma("unroll")                                                       \
        for (int c = 0; c < 4; c++)                                             \
            a_[c] = (kb + c * 16 + l15 <= qrow) ? sv[c][r] * scl : -1e30f;      \
        float mx = fmaxf(fmaxf(a_[0], a_[1]), fmaxf(a_[2], a_[3]));             \
        _Pragma("unroll")                                                       \
        for (int sh = 1; sh < 16; sh <<= 1) mx = fmaxf(mx, __shfl_xor(mx, sh)); \
        const float mn = fmaxf(mv[r], mx);                                      \
        const float alpha = __expf(mv[r] - mn);                                 \
        mv[r] = mn;                                                             \
        float rs = 0.f;                                                         \
        _Pragma("unroll")                                                       \
        for (int c = 0; c < 4; c++) {                                           \
            const float e = __expf(a_[c] - mn);                                 \
            rs += e;                                                            \
            Ps[w][(prow) + l4 * 4 + r][c * 16 + l15] = (HT)e;                   \
        }                                                                       \
        _Pragma("unroll")                                                       \
        for (int sh = 1; sh < 16; sh <<= 1) rs += __shfl_xor(rs, sh);           \
        lv[r] = lv[r] * alpha + rs;                                             \
        al_[r] = alpha;                                                         \
    }                                                                           \
    _Pragma("unroll")                                                           \
    for (int g = 0; g < 8; g++)                                                 \
        _Pragma("unroll")                                                       \
        for (int r = 0; r < 4; r++) ov[g][r] *= al_[r];                         \
}

#define KBODY(ACT0)                                                             \
{                                                                               \
    f32x4 s0[4] = {}, s1[4] = {};                                               \
    __builtin_amdgcn_s_setprio(1);                                              \
    _Pragma("unroll")                                                           \
    for (int c = 0; c < 4; c++) {                                               \
        const int kr = c * 16 + l15;                                            \
        const HT* rp = krb + (size_t)(kb + kr) * 64 + l4 * 8;                   \
        const h8 br0 = *reinterpret_cast<const h8*>(rp);                        \
        const h8 br1 = *reinterpret_cast<const h8*>(rp + 32);                   \
        const int sw = (kr & 7) << 4;                                           \
        const char* kbase = (const char*)Ks_n + kr * 256;                       \
        _Pragma("unroll")                                                       \
        for (int f = 0; f < 4; f++) {                                           \
            const h8 kf = *(const h8*)(kbase + ((f * 64 + l4 * 16) ^ sw));      \
            s1[c] = mfma16(aq1[f], kf, s1[c]);                                  \
            if (ACT0) s0[c] = mfma16(aq0[f], kf, s0[c]);                        \
        }                                                                       \
        s1[c] = mfma16(aq1[4], br0, s1[c]);                                     \
        s1[c] = mfma16(aq1[5], br1, s1[c]);                                     \
        if (ACT0) { s0[c] = mfma16(aq0[4], br0, s0[c]);                         \
                    s0[c] = mfma16(aq0[5], br1, s0[c]); }                       \
    }                                                                           \
    __builtin_amdgcn_s_setprio(0);                                              \
    SOFTMAX(s1, m1v, l1v, o1, qw1, 16);                                         \
    if (ACT0) SOFTMAX(s0, m0v, l0v, o0, qw0, 0);                                \
    const h8 ap10 = *reinterpret_cast<const h8*>(&Ps[w][16 + l15][l4 * 8]);     \
    const h8 ap11 = *reinterpret_cast<const h8*>(&Ps[w][16 + l15][32 + l4 * 8]);\
    h8 ap00 = ap10, ap01 = ap11;                                                \
    if (ACT0) {                                                                 \
        ap00 = *reinterpret_cast<const h8*>(&Ps[w][l15][l4 * 8]);               \
        ap01 = *reinterpret_cast<const h8*>(&Ps[w][l15][32 + l4 * 8]);          \
    }                                                                           \
    __builtin_amdgcn_s_setprio(1);                                              \
    _Pragma("unroll")                                                           \
    for (int g = 0; g < 8; g++) {                                               \
        const int d = g * 16 + l15;                                             \
        const int sw = (d & 7) << 4;                                            \
        const char* vbase = (const char*)Vs + d * 128;                          \
        const h8 v0 = *(const h8*)(vbase + ((l4 * 16) ^ sw));                   \
        const h8 v1 = *(const h8*)(vbase + ((64 + l4 * 16) ^ sw));              \
        o1[g] = mfma16(ap10, v0, o1[g]);                                        \
        o1[g] = mfma16(ap11, v1, o1[g]);                                        \
        if (ACT0) { o0[g] = mfma16(ap00, v0, o0[g]);                            \
                    o0[g] = mfma16(ap01, v1, o0[g]); }                          \
    }                                                                           \
    __builtin_amdgcn_s_setprio(0);                                              \
}

    const int nkb = thi + 1;
    for (int kb64 = 0; kb64 < nkb; kb64++) {
        const int kb = kb64 * 64;
        __syncthreads();
        // ---- cooperative stage: K-nope + V^T (8 chunks per wave) ----
        #pragma unroll
        for (int jj = 0; jj < 4; jj++) {          // K nope 16KB (16 chunks)
            const int r = (w * 4 + jj) * 4 + l4;
            const int cl = (l15 & 8) | ((l15 & 7) ^ (r & 7));
            gload_lds16(kn + (bT + kb + r) * 2048 + h * 128 + cl * 8,
                        &Ks_n[(w * 4 + jj) * 512]);
        }
        #pragma unroll
        for (int jj = 0; jj < 4; jj++) {          // V^T 16KB (16 chunks)
            const int d = (w * 4 + jj) * 8 + (lane >> 3);
            const int cl = (lane & 7) ^ (d & 7);
            gload_lds16(vt_h + (size_t)d * Tn + kb + cl * 8,
                        &Vs[(w * 4 + jj) * 512]);
        }
        __syncthreads();

        // qf1 active every iteration (kb <= thi*64 <= qw1+15); qf0 wave-uniform
        if (kb <= qw0 + 15) KBODY(1) else KBODY(0)
    }
#undef KBODY
#undef SOFTMAX

    // ---- normalize + store both q-groups ----
    {
        const size_t orow = bT + qw1 + l4 * 4;
        #pragma unroll
        for (int r = 0; r < 4; r++) {
            const float inv = 1.0f / l1v[r];
            HT* dst = ao + (orow + r) * 2048 + h * 128 + l15;
            #pragma unroll
            for (int g = 0; g < 8; g++) dst[g * 16] = (HT)(o1[g][r] * inv);
        }
    }
    {
        const size_t orow = bT + qw0 + l4 * 4;
        #pragma unroll
        for (int r = 0; r < 4; r++) {
            const float inv = 1.0f / l0v[r];
            HT* dst = ao + (orow + r) * 2048 + h * 128 + l15;
            #pragma unroll
            for (int g = 0; g < 8; g++) dst[g * 16] = (HT)(o0[g][r] * inv);
        }
    }
}

// ---------------------------------------------------------------------------
extern "C" void kernel_launch(void* const* d_in, const int* in_sizes, int n_in,
                              void* d_out, int out_size, void* d_ws, size_t ws_size,
                              hipStream_t stream)
{
    const float* x     = (const float*)d_in[0];
    const float* w_cq  = (const float*)d_in[1];
    const float* g_q   = (const float*)d_in[2];
    const float* w_ckv = (const float*)d_in[3];
    const float* g_kv  = (const float*)d_in[4];
    const float* w_dqn = (const float*)d_in[5];
    const float* w_dqr = (const float*)d_in[6];
    const float* w_dkn = (const float*)d_in[7];
    const float* w_dv  = (const float*)d_in[8];
    const float* w_kr  = (const float*)d_in[9];
    const float* w_out = (const float*)d_in[10];

    char* ws = (char*)d_ws;
    // weight region (dead after their GEMM -> vt aliases it)
    HT* cqT   = (HT*)(ws + 0);           // [1536][2048]  6,291,456
    HT* ckvT  = (HT*)(ws + 6291456);     // [512][2048]   2,097,152
    HT* krT   = (HT*)(ws + 8388608);     // [64][2048]      262,144
    //  pad region [8650752, 8912896) read as garbage B rows (never written out)
    HT* dqnT  = (HT*)(ws + 8912896);     // [2048][1536]  6,291,456
    HT* dqrT  = (HT*)(ws + 15204352);    // [1024][1536]  3,145,728
    HT* dknT  = (HT*)(ws + 18350080);    // [2048][512]   2,097,152
    HT* dvT   = (HT*)(ws + 20447232);    // [2048][512]   2,097,152
    HT* outT  = (HT*)(ws + 22544384);    // [2048][2048]  8,388,608
    HT* cq    = (HT*)(ws + 30932992);    // [4096][1536] 12,582,912
    HT* ckv   = (HT*)(ws + 43515904);    // [4096][512]   4,194,304
    HT* qn    = (HT*)(ws + 47710208);    // [4096][2048] 16,777,216 (x16/ao alias)
    HT* qr    = (HT*)(ws + 64487424);    // [4096][1024]  8,388,608
    HT* kn    = (HT*)(ws + 72876032);    // [4096][2048] 16,777,216
    HT* kr16  = (HT*)(ws + 89653248);    // [4096][64]      524,288  (end 90,177,536)
    HT* vt    = (HT*)(ws + 0);           // [2][16][128][2048] 16,777,216 (alias)
    HT* x16   = qn;                      // x16 dead before qn written
    HT* ao    = qn;                      // attn reads/writes same (row,h) slice

    float* out_o = (float*)d_out;
    float* out_k = out_o + (size_t)BT * Dm;
    float* out_v = out_k + (size_t)2 * Hh * Tn * 192;
    float2* cstab = (float2*)out_v;      // stashed in out_v head; KV GEMM
                                         // overwrites it AFTER last use (Q GEMM)

    const dim3 blk(256);

    cstab_kernel<<<dim3(256), blk, 0, stream>>>(cstab);

    // merged weight transposes: src [K][N] -> dst [N][K]
    WT8 wt;
    wt.s[0]=w_cq;  wt.d[0]=cqT;  wt.K[0]=2048; wt.N[0]=1536;
    wt.s[1]=w_ckv; wt.d[1]=ckvT; wt.K[1]=2048; wt.N[1]=512;
    wt.s[2]=w_kr;  wt.d[2]=krT;  wt.K[2]=2048; wt.N[2]=64;
    wt.s[3]=w_dqn; wt.d[3]=dqnT; wt.K[3]=1536; wt.N[3]=2048;
    wt.s[4]=w_dqr; wt.d[4]=dqrT; wt.K[4]=1536; wt.N[4]=1024;
    wt.s[5]=w_dkn; wt.d[5]=dknT; wt.K[5]=512;  wt.N[5]=2048;
    wt.s[6]=w_dv;  wt.d[6]=dvT;  wt.K[6]=512;  wt.N[6]=2048;
    wt.s[7]=w_out; wt.d[7]=outT; wt.K[7]=2048; wt.N[7]=2048;
    {
        int acc = 0;
        for (int i = 0; i < 8; i++) {
            wt.start[i] = acc;
            acc += (wt.N[i] >> 6) * (wt.K[i] >> 6);
        }
        wtrans8_kernel<<<dim3(acc), blk, 0, stream>>>(wt);   // acc = 3744
    }

    convx_kernel<<<dim3(4096), blk, 0, stream>>>(x, x16);

    // fused latent GEMM: N=2176 (cq | ckv | kr16-rope | pad)
    gemm16d<0><<<dim3(17, BT/128), blk, 0, stream>>>(x16, cqT, Dm,
        cq, ckv, kr16, nullptr, nullptr, cstab);
    kropebc_kernel<<<dim3(256), blk, 0, stream>>>(kr16, out_k);

    rmsnorm2_kernel<<<dim3(BT, 2), blk, 0, stream>>>(cq, g_q, ckv, g_kv);

    // fused Q GEMM: N=3072 (qn | qr-rope)  [reads cstab; must precede KV GEMM]
    gemm16d<1><<<dim3(24, BT/128), blk, 0, stream>>>(cq, dqnT, QRc,
        qn, qr, nullptr, nullptr, nullptr, cstab);
    // fused KV GEMM: N=4096 (kn+out_k | vt+out_v)  [overwrites cstab & weight region]
    gemm16d<2><<<dim3(32, BT/128), blk, 0, stream>>>(ckv, dknT, KVRc,
        kn, nullptr, vt, out_k, out_v, nullptr);

    // attention (mirrored-tile QBLK=32 waves, uniform 33 k-blocks per wave)
    attn7_kernel<<<dim3(512), blk, 0, stream>>>(qn, qr, kn, kr16, vt, ao);

    // output projection
    gemm16d<3><<<dim3(16, BT/128), blk, 0, stream>>>(ao, outT, Dm,
        nullptr, nullptr, nullptr, out_o, nullptr, nullptr);
}